// Round 17
// baseline (198.931 us; speedup 1.0000x reference)
//
#include <hip/hip_runtime.h>

typedef unsigned short u16;
using bf16x8 = __attribute__((ext_vector_type(8))) __bf16;
using f32x4  = __attribute__((ext_vector_type(4))) float;

// SCALE * log2(e): softmax runs in exp2 domain
#define QSCALE 0.18033688011f

#define EXP2F(x) __builtin_amdgcn_exp2f(x)
#define SCHED_FENCE() __builtin_amdgcn_sched_barrier(0)

__device__ __forceinline__ u16 f2bf(float f) {
  union { float f; unsigned int u; } x; x.f = f;
  unsigned int r = x.u + 0x7FFFu + ((x.u >> 16) & 1u);
  return (u16)(r >> 16);
}

__device__ __forceinline__ bf16x8 ld8(const u16* p) {
  return *reinterpret_cast<const bf16x8*>(p);
}

__device__ __forceinline__ void gload16(const void* g, void* l) {
  __builtin_amdgcn_global_load_lds(
      (const __attribute__((address_space(1))) unsigned int*)g,
      (__attribute__((address_space(3))) unsigned int*)l, 16, 0, 0);
}

// 3 activation tensors in one launch; outputs contiguous at out + y*n4*4
__global__ void cast3_f32_to_bf16(const float* __restrict__ a, const float* __restrict__ b,
                                  const float* __restrict__ c, u16* __restrict__ out, int n4) {
  const int y = blockIdx.y;
  const int i = blockIdx.x * 256 + threadIdx.x;
  if (i >= n4) return;
  const float* src = (y == 0) ? a : (y == 1) ? b : c;
  const float4 v = reinterpret_cast<const float4*>(src)[i];
  ushort4 o;
  o.x = f2bf(v.x); o.y = f2bf(v.y); o.z = f2bf(v.z); o.w = f2bf(v.w);
  reinterpret_cast<ushort4*>(out + (size_t)y * n4 * 4)[i] = o;
}

__global__ void cast4_f32_to_bf16(const float* __restrict__ a, const float* __restrict__ b,
                                  const float* __restrict__ c, const float* __restrict__ d,
                                  u16* __restrict__ out, int n4) {
  const int y = blockIdx.y;
  const int i = blockIdx.x * 256 + threadIdx.x;
  if (i >= n4) return;
  const float* src = (y == 0) ? a : (y == 1) ? b : (y == 2) ? c : d;
  const float4 v = reinterpret_cast<const float4*>(src)[i];
  ushort4 o;
  o.x = f2bf(v.x); o.y = f2bf(v.y); o.z = f2bf(v.z); o.w = f2bf(v.w);
  reinterpret_cast<ushort4*>(out + (size_t)y * n4 * 4)[i] = o;
}

// ---- m97 GEMM core (128x128 tile, BK=32, gload_lds w=16, 2-barrier) ----
#define GEMM_CORE(A_, B_, K_, BX_, BY_)                                              \
  __shared__ alignas(16) u16 lds_a[128 * 32];                                        \
  __shared__ alignas(16) u16 lds_b[128 * 32];                                        \
  const int t = threadIdx.x;                                                         \
  const int w = t >> 6, lane = t & 63;                                               \
  const int wr = w >> 1, wc = w & 1;                                                 \
  const size_t row0 = (size_t)(BY_) * 128;                                           \
  const size_t col0 = (size_t)(BX_) * 128;                                           \
  f32x4 acc[4][4];                                                                   \
  _Pragma("unroll") for (int i = 0; i < 4; ++i)                                      \
    _Pragma("unroll") for (int j = 0; j < 4; ++j) acc[i][j] = {0.f, 0.f, 0.f, 0.f};  \
  const u16* ga = A_ + (row0 + (t >> 2)) * K_ + (t & 3) * 8;                         \
  const u16* gb = B_ + (col0 + (t >> 2)) * K_ + (t & 3) * 8;                         \
  u16* la = lds_a + w * 512;                                                         \
  u16* lb = lds_b + w * 512;                                                         \
  const int fr = lane & 15;                                                          \
  const int fk = (lane >> 4) * 8;                                                    \
  for (int kt = 0; kt < K_; kt += 32) {                                              \
    __syncthreads();                                                                 \
    gload16(ga + kt, la);                                                            \
    gload16(ga + (size_t)64 * K_ + kt, la + 2048);                                   \
    gload16(gb + kt, lb);                                                            \
    gload16(gb + (size_t)64 * K_ + kt, lb + 2048);                                   \
    asm volatile("s_waitcnt vmcnt(0)" ::: "memory");                                 \
    __syncthreads();                                                                 \
    bf16x8 af[4], bfr[4];                                                            \
    _Pragma("unroll") for (int i = 0; i < 4; ++i)                                    \
      af[i] = ld8(&lds_a[(wr * 64 + i * 16 + fr) * 32 + fk]);                        \
    _Pragma("unroll") for (int j = 0; j < 4; ++j)                                    \
      bfr[j] = ld8(&lds_b[(wc * 64 + j * 16 + fr) * 32 + fk]);                       \
    _Pragma("unroll") for (int i = 0; i < 4; ++i)                                    \
      _Pragma("unroll") for (int j = 0; j < 4; ++j)                                  \
        acc[i][j] = __builtin_amdgcn_mfma_f32_16x16x32_bf16(af[i], bfr[j], acc[i][j], 0, 0, 0); \
  }                                                                                  \
  const int er = (lane >> 4) * 4, ec = lane & 15;

// ---- counted-vmcnt GEMM core, BM=128 x BN=256, BK=64, 8 waves, 3 LDS bufs ----
// T4 for real: tile t+2's 6 loads issued at top of tile t; wait at top of tile
// t is vmcnt(6) (tile t+1's 6 stay in flight; FIFO drain per m135). Issue-to-
// wait distance = 2 tiles > HBM latency. WAR: buf[(t+2)%3]'s last reader is
// tile t-1, done before the top-of-t barrier. Fragment/swizzle math identical
// to the bit-exact r16 core (source chunk ^=(t>>4)&2, read XOR (fr&4)<<2).
__device__ __forceinline__ void gemm8c_core(const u16* __restrict__ A, const u16* __restrict__ B,
                                            int by, int bx, f32x4 (&acc)[4][4],
                                            u16 (*lds_a)[8192], u16 (*lds_b)[16384]) {
  const int t = threadIdx.x;
  const int w = t >> 6, lane = t & 63;
  const int wm = w >> 2, wn = w & 3;
  const int fr = lane & 15, lh = lane >> 4;
  const int xr = (fr & 4) << 2;
  const int kch = ((t & 7) ^ ((t >> 4) & 2)) * 8;

  const u16* ga = A + (size_t)(by * 128 + (t >> 3)) * 1024 + kch;
  const u16* gb = B + (size_t)(bx * 256 + (t >> 3)) * 1024 + kch;

#pragma unroll
  for (int m = 0; m < 4; ++m)
#pragma unroll
    for (int n = 0; n < 4; ++n) acc[m][n] = {0.f, 0.f, 0.f, 0.f};

#define STAGE6(tile, buf)                                                      \
  do {                                                                         \
    gload16(ga + (size_t)0 * 65536 + (tile) * 64, &lds_a[buf][0 * 4096 + w * 512]); \
    gload16(ga + (size_t)1 * 65536 + (tile) * 64, &lds_a[buf][1 * 4096 + w * 512]); \
    gload16(gb + (size_t)0 * 65536 + (tile) * 64, &lds_b[buf][0 * 4096 + w * 512]); \
    gload16(gb + (size_t)1 * 65536 + (tile) * 64, &lds_b[buf][1 * 4096 + w * 512]); \
    gload16(gb + (size_t)2 * 65536 + (tile) * 64, &lds_b[buf][2 * 4096 + w * 512]); \
    gload16(gb + (size_t)3 * 65536 + (tile) * 64, &lds_b[buf][3 * 4096 + w * 512]); \
  } while (0)

  // prologue: tiles 0,1 in flight
  STAGE6(0, 0);
  STAGE6(1, 1);

  int buf = 0;       // consume buffer for tile kt
  int sbuf = 2;      // stage buffer for tile kt+2
  for (int kt = 0; kt < 16; ++kt) {
    if (kt < 15) { asm volatile("s_waitcnt vmcnt(6)" ::: "memory"); }
    else         { asm volatile("s_waitcnt vmcnt(0)" ::: "memory"); }
    __builtin_amdgcn_s_barrier();
    SCHED_FENCE();
    if (kt < 14) STAGE6(kt + 2, sbuf);
    SCHED_FENCE();

    bf16x8 bfr[4][2];
#pragma unroll
    for (int nn = 0; nn < 4; ++nn)
#pragma unroll
      for (int ks = 0; ks < 2; ++ks)
        bfr[nn][ks] = ld8(&lds_b[buf][(wn * 64 + nn * 16 + fr) * 64 + ((ks * 32 + lh * 8) ^ xr)]);
#pragma unroll
    for (int q = 0; q < 4; ++q) {
      if (q) __builtin_amdgcn_s_barrier();   // keep waves phase-interleaved
      bf16x8 af[2];
#pragma unroll
      for (int ks = 0; ks < 2; ++ks)
        af[ks] = ld8(&lds_a[buf][(wm * 64 + q * 16 + fr) * 64 + ((ks * 32 + lh * 8) ^ xr)]);
      __builtin_amdgcn_s_setprio(1);
#pragma unroll
      for (int nn = 0; nn < 4; ++nn)
#pragma unroll
        for (int ks = 0; ks < 2; ++ks)
          acc[q][nn] = __builtin_amdgcn_mfma_f32_16x16x32_bf16(af[ks], bfr[nn][ks], acc[q][nn], 0, 0, 0);
      __builtin_amdgcn_s_setprio(0);
    }
    buf = (buf == 2) ? 0 : buf + 1;
    sbuf = (sbuf == 2) ? 0 : sbuf + 1;
  }
#undef STAGE6
}

// Q/K/V projections, counted-vmcnt core. Grid 768 = 8 XCD x 96 = 3.0/CU.
// z=0: Q * QSCALE. z=1: K per-row chunk XOR. z=2: V^T + PV key perm + XOR.
__global__ __launch_bounds__(512)
void gemm8_qkv(const u16* __restrict__ Aall, const u16* __restrict__ Ball,
               u16* __restrict__ Call) {
  __shared__ alignas(16) u16 lds_a[3][8192];
  __shared__ alignas(16) u16 lds_b[3][16384];
  const int g = (blockIdx.x & 7) * 96 + (blockIdx.x >> 3);
  const int z = g >> 8, r8 = g & 255;
  const int by = r8 >> 2, bx = r8 & 3;
  const u16* A = Aall + (size_t)z * 8192 * 1024;
  const u16* B = Ball + (size_t)z * 1024 * 1024;
  u16* C = Call + (size_t)z * 8192 * 1024;

  f32x4 acc[4][4];
  gemm8c_core(A, B, by, bx, acc, lds_a, lds_b);

  const int t = threadIdx.x;
  const int w = t >> 6, lane = t & 63;
  const int wm = w >> 2, wn = w & 3;
  const int er = (lane >> 4) * 4, ec = lane & 15;
#pragma unroll
  for (int m = 0; m < 4; ++m)
#pragma unroll
    for (int nn = 0; nn < 4; ++nn) {
      const size_t row = (size_t)by * 128 + wm * 64 + m * 16 + er;
      const size_t col = (size_t)bx * 256 + wn * 64 + nn * 16 + ec;
      if (z == 0) {
#pragma unroll
        for (int rr = 0; rr < 4; ++rr)
          C[(row + rr) * 1024 + col] = f2bf(acc[m][nn][rr] * QSCALE);
      } else if (z == 1) {
        // K: swizzle dim chunk (8 dims = 16B) within head by key&7
#pragma unroll
        for (int rr = 0; rr < 4; ++rr) {
          const size_t n = row + rr;
          const size_t colswz = (col & ~(size_t)63) | ((col & 63) ^ ((n & 7) << 3));
          C[n * 1024 + colswz] = f2bf(acc[m][nn][rr]);
        }
      } else {
        // V^T per head: PV key permutation + key-chunk XOR by dim&7.
        ushort4 o4;
        o4.x = f2bf(acc[m][nn][0]); o4.y = f2bf(acc[m][nn][1]);
        o4.z = f2bf(acc[m][nn][2]); o4.w = f2bf(acc[m][nn][3]);
        const size_t nloc = row & 2047;
        const size_t d = col & 63;
        size_t pos = (nloc & ~(size_t)31) | (((nloc >> 2) & 3) << 3) |
                     (((nloc >> 4) & 1) << 2) | (nloc & 3);
        pos ^= (d & 7) << 3;
        const size_t idx = (((row >> 11) * 16 + (col >> 6)) * 64 + d) * 2048 + pos;
        *reinterpret_cast<ushort4*>(&C[idx]) = o4;
      }
    }
}

// Out-projection: m97 core (proven), f32 out + bias; grid 512 = 2.0/CU, XCD swizzle.
__global__ __launch_bounds__(256)
void gemm_out(const u16* __restrict__ A, const u16* __restrict__ B,
              float* __restrict__ Cf, const float* __restrict__ bias) {
  const int g = (blockIdx.x & 7) * 64 + (blockIdx.x >> 3);
  const int bx = g & 7, by = g >> 3;
  GEMM_CORE(A, B, 1024, bx, by)
#pragma unroll
  for (int i = 0; i < 4; ++i)
#pragma unroll
    for (int j = 0; j < 4; ++j) {
      const size_t row = row0 + wr * 64 + i * 16 + er;
      const size_t col = col0 + wc * 64 + j * 16 + ec;
#pragma unroll
      for (int r = 0; r < 4; ++r)
        Cf[(row + r) * 1024 + col] = acc[i][j][r] + bias[col];
    }
}

// Flash attention v9 (race-hardened, proven r13-r16 — unchanged).
__global__ __launch_bounds__(512)
void flash_attn(const u16* __restrict__ Q, const u16* __restrict__ Km,
                const u16* __restrict__ Vt, u16* __restrict__ O) {
  const int o_blk = (blockIdx.x & 7) * 64 + (blockIdx.x >> 3);
  const int qt = o_blk & 7, h = (o_blk >> 3) & 15, b = o_blk >> 7;
  const int t = threadIdx.x;
  const int w = t >> 6, lane = t & 63;
  const int l16 = lane & 15, lh = lane >> 4;

  __shared__ alignas(16) u16 kt_lds[2][64][64];
  __shared__ alignas(16) u16 vt_lds[2][64][64];

  const size_t base_qk = ((size_t)b * 2048) * 1024 + (size_t)h * 64;
  const size_t base_vt = ((size_t)(b * 16 + h)) * 64 * 2048;

  bf16x8 qf[2][2];
#pragma unroll
  for (int g = 0; g < 2; ++g) {
    const size_t qrow = (size_t)qt * 256 + (w * 2 + g) * 16 + l16;
    const u16* qp = Q + base_qk + qrow * 1024 + lh * 8;
    qf[g][0] = ld8(qp);
    qf[g][1] = ld8(qp + 32);
  }

  bf16x8 vones;
#pragma unroll
  for (int i = 0; i < 8; ++i) vones[i] = (__bf16)1.0f;

  f32x4 o_acc[2][4];
  f32x4 o_sum[2];
#pragma unroll
  for (int g = 0; g < 2; ++g) {
#pragma unroll
    for (int j = 0; j < 4; ++j) o_acc[g][j] = {0.f, 0.f, 0.f, 0.f};
    o_sum[g] = {0.f, 0.f, 0.f, 0.f};
  }

  const int srow = t >> 3;
  const int schk = (t & 7) * 8;
  const u16* kg = Km + base_qk + (size_t)srow * 1024 + schk;
  const u16* vg = Vt + base_vt + (size_t)srow * 2048 + schk;
  u16* kl0 = &kt_lds[0][0][0] + w * 512;
  u16* kl1 = &kt_lds[1][0][0] + w * 512;
  u16* vl0 = &vt_lds[0][0][0] + w * 512;
  u16* vl1 = &vt_lds[1][0][0] + w * 512;

  gload16(kg, kl0);
  gload16(vg, vl0);

  const int xo = (l16 & 7) << 3;

  for (int it = 0; it < 32; ++it) {
    const int cur = it & 1;
    asm volatile("s_waitcnt vmcnt(0)" ::: "memory");
    SCHED_FENCE();
    __syncthreads();
    SCHED_FENCE();

    if (it != 31) {
      const int nkv = (it + 1) * 64;
      gload16(kg + (size_t)nkv * 1024, cur ? kl0 : kl1);
      gload16(vg + nkv, cur ? vl0 : vl1);
    }
    SCHED_FENCE();

    f32x4 s[2][4];
#pragma unroll
    for (int g = 0; g < 2; ++g)
#pragma unroll
      for (int j = 0; j < 4; ++j) s[g][j] = {0.f, 0.f, 0.f, 0.f};
    __builtin_amdgcn_s_setprio(1);
#pragma unroll
    for (int j = 0; j < 4; ++j)
#pragma unroll
      for (int ks = 0; ks < 2; ++ks) {
        bf16x8 kf = ld8(&kt_lds[cur][j * 16 + l16][(ks * 32 + lh * 8) ^ xo]);
        s[0][j] = __builtin_amdgcn_mfma_f32_16x16x32_bf16(kf, qf[0][ks], s[0][j], 0, 0, 0);
        s[1][j] = __builtin_amdgcn_mfma_f32_16x16x32_bf16(kf, qf[1][ks], s[1][j], 0, 0, 0);
      }
    __builtin_amdgcn_s_setprio(0);

    bf16x8 pa[2][2];
#pragma unroll
    for (int g = 0; g < 2; ++g)
#pragma unroll
      for (int j = 0; j < 4; ++j)
#pragma unroll
        for (int r = 0; r < 4; ++r)
          s[g][j][r] = EXP2F(s[g][j][r]);
#pragma unroll
    for (int g = 0; g < 2; ++g)
#pragma unroll
      for (int c = 0; c < 2; ++c)
#pragma unroll
        for (int i = 0; i < 8; ++i)
          pa[g][c][i] = (__bf16)s[g][2 * c + (i >> 2)][i & 3];

    __builtin_amdgcn_s_setprio(1);
#pragma unroll
    for (int c = 0; c < 2; ++c) {
      o_sum[0] = __builtin_amdgcn_mfma_f32_16x16x32_bf16(pa[0][c], vones, o_sum[0], 0, 0, 0);
      o_sum[1] = __builtin_amdgcn_mfma_f32_16x16x32_bf16(pa[1][c], vones, o_sum[1], 0, 0, 0);
#pragma unroll
      for (int jd = 0; jd < 4; ++jd) {
        bf16x8 vf = ld8(&vt_lds[cur][jd * 16 + l16][(c * 32 + lh * 8) ^ xo]);
        o_acc[0][jd] = __builtin_amdgcn_mfma_f32_16x16x32_bf16(pa[0][c], vf, o_acc[0][jd], 0, 0, 0);
        o_acc[1][jd] = __builtin_amdgcn_mfma_f32_16x16x32_bf16(pa[1][c], vf, o_acc[1][jd], 0, 0, 0);
      }
    }
    __builtin_amdgcn_s_setprio(0);
  }

#pragma unroll
  for (int g = 0; g < 2; ++g) {
    float linv[4];
#pragma unroll
    for (int r = 0; r < 4; ++r) linv[r] = 1.0f / o_sum[g][r];
    const size_t orow0 = (size_t)b * 2048 + (size_t)qt * 256 + (w * 2 + g) * 16;
#pragma unroll
    for (int jd = 0; jd < 4; ++jd) {
      const int col = h * 64 + jd * 16 + l16;
#pragma unroll
      for (int r = 0; r < 4; ++r)
        O[(orow0 + lh * 4 + r) * 1024 + col] = f2bf(o_acc[g][jd][r] * linv[r]);
    }
  }
}

extern "C" void kernel_launch(void* const* d_in, const int* in_sizes, int n_in,
                              void* d_out, int out_size, void* d_ws, size_t ws_size,
                              hipStream_t stream) {
  const float* xq = (const float*)d_in[0];
  const float* xk = (const float*)d_in[1];
  const float* xv = (const float*)d_in[2];
  const float* Wq = (const float*)d_in[3];
  const float* Wk = (const float*)d_in[4];
  const float* Wv = (const float*)d_in[5];
  const float* Wo = (const float*)d_in[6];
  const float* bo = (const float*)d_in[7];
  float* out = (float*)d_out;

  const size_t X = (size_t)8192 * 1024;
  const size_t W = (size_t)1024 * 1024;

  u16* p = (u16*)d_ws;
  u16* x_bf  = p; p += 3 * X;          // xq | xk | xv (contiguous)
  u16* w_bf  = p; p += 4 * W;          // Wq | Wk | Wv | Wo
  u16* qkv   = p; p += 3 * X;          // Q | K(swz) | V^T(swz)
  u16* attn_bf = x_bf;                  // x_bf dead after projections; reuse

  dim3 blk(256);
  cast3_f32_to_bf16<<<dim3(8192, 3), blk, 0, stream>>>(xq, xk, xv, x_bf, (int)(X / 4));
  cast4_f32_to_bf16<<<dim3(1024, 4), blk, 0, stream>>>(Wq, Wk, Wv, Wo, w_bf, (int)(W / 4));

  gemm8_qkv<<<dim3(768), dim3(512), 0, stream>>>(x_bf, w_bf, qkv);

  flash_attn<<<dim3(512), dim3(512), 0, stream>>>(qkv, qkv + X, qkv + 2 * X, attn_bf);

  gemm_out<<<dim3(512), blk, 0, stream>>>(attn_bf, w_bf + 3 * W, out, bo);
}

// Round 18
// 198.732 us; speedup vs baseline: 1.0010x; 1.0010x over previous
//
#include <hip/hip_runtime.h>

typedef unsigned short u16;
using bf16x8 = __attribute__((ext_vector_type(8))) __bf16;
using f32x4  = __attribute__((ext_vector_type(4))) float;

// SCALE * log2(e): softmax runs in exp2 domain
#define QSCALE 0.18033688011f

#define EXP2F(x) __builtin_amdgcn_exp2f(x)
#define SCHED_FENCE() __builtin_amdgcn_sched_barrier(0)

__device__ __forceinline__ u16 f2bf(float f) {
  union { float f; unsigned int u; } x; x.f = f;
  unsigned int r = x.u + 0x7FFFu + ((x.u >> 16) & 1u);
  return (u16)(r >> 16);
}

__device__ __forceinline__ bf16x8 ld8(const u16* p) {
  return *reinterpret_cast<const bf16x8*>(p);
}

__device__ __forceinline__ void gload16(const void* g, void* l) {
  __builtin_amdgcn_global_load_lds(
      (const __attribute__((address_space(1))) unsigned int*)g,
      (__attribute__((address_space(3))) unsigned int*)l, 16, 0, 0);
}

// 3 activation tensors in one launch; outputs contiguous at out + y*n4*4
__global__ void cast3_f32_to_bf16(const float* __restrict__ a, const float* __restrict__ b,
                                  const float* __restrict__ c, u16* __restrict__ out, int n4) {
  const int y = blockIdx.y;
  const int i = blockIdx.x * 256 + threadIdx.x;
  if (i >= n4) return;
  const float* src = (y == 0) ? a : (y == 1) ? b : c;
  const float4 v = reinterpret_cast<const float4*>(src)[i];
  ushort4 o;
  o.x = f2bf(v.x); o.y = f2bf(v.y); o.z = f2bf(v.z); o.w = f2bf(v.w);
  reinterpret_cast<ushort4*>(out + (size_t)y * n4 * 4)[i] = o;
}

__global__ void cast4_f32_to_bf16(const float* __restrict__ a, const float* __restrict__ b,
                                  const float* __restrict__ c, const float* __restrict__ d,
                                  u16* __restrict__ out, int n4) {
  const int y = blockIdx.y;
  const int i = blockIdx.x * 256 + threadIdx.x;
  if (i >= n4) return;
  const float* src = (y == 0) ? a : (y == 1) ? b : (y == 2) ? c : d;
  const float4 v = reinterpret_cast<const float4*>(src)[i];
  ushort4 o;
  o.x = f2bf(v.x); o.y = f2bf(v.y); o.z = f2bf(v.z); o.w = f2bf(v.w);
  reinterpret_cast<ushort4*>(out + (size_t)y * n4 * 4)[i] = o;
}

// ---- m97 GEMM core (128x128 tile, BK=32, gload_lds w=16, 2-barrier) ----
#define GEMM_CORE(A_, B_, K_, BX_, BY_)                                              \
  __shared__ alignas(16) u16 lds_a[128 * 32];                                        \
  __shared__ alignas(16) u16 lds_b[128 * 32];                                        \
  const int t = threadIdx.x;                                                         \
  const int w = t >> 6, lane = t & 63;                                               \
  const int wr = w >> 1, wc = w & 1;                                                 \
  const size_t row0 = (size_t)(BY_) * 128;                                           \
  const size_t col0 = (size_t)(BX_) * 128;                                           \
  f32x4 acc[4][4];                                                                   \
  _Pragma("unroll") for (int i = 0; i < 4; ++i)                                      \
    _Pragma("unroll") for (int j = 0; j < 4; ++j) acc[i][j] = {0.f, 0.f, 0.f, 0.f};  \
  const u16* ga = A_ + (row0 + (t >> 2)) * K_ + (t & 3) * 8;                         \
  const u16* gb = B_ + (col0 + (t >> 2)) * K_ + (t & 3) * 8;                         \
  u16* la = lds_a + w * 512;                                                         \
  u16* lb = lds_b + w * 512;                                                         \
  const int fr = lane & 15;                                                          \
  const int fk = (lane >> 4) * 8;                                                    \
  for (int kt = 0; kt < K_; kt += 32) {                                              \
    __syncthreads();                                                                 \
    gload16(ga + kt, la);                                                            \
    gload16(ga + (size_t)64 * K_ + kt, la + 2048);                                   \
    gload16(gb + kt, lb);                                                            \
    gload16(gb + (size_t)64 * K_ + kt, lb + 2048);                                   \
    asm volatile("s_waitcnt vmcnt(0)" ::: "memory");                                 \
    __syncthreads();                                                                 \
    bf16x8 af[4], bfr[4];                                                            \
    _Pragma("unroll") for (int i = 0; i < 4; ++i)                                    \
      af[i] = ld8(&lds_a[(wr * 64 + i * 16 + fr) * 32 + fk]);                        \
    _Pragma("unroll") for (int j = 0; j < 4; ++j)                                    \
      bfr[j] = ld8(&lds_b[(wc * 64 + j * 16 + fr) * 32 + fk]);                       \
    _Pragma("unroll") for (int i = 0; i < 4; ++i)                                    \
      _Pragma("unroll") for (int j = 0; j < 4; ++j)                                  \
        acc[i][j] = __builtin_amdgcn_mfma_f32_16x16x32_bf16(af[i], bfr[j], acc[i][j], 0, 0, 0); \
  }                                                                                  \
  const int er = (lane >> 4) * 4, ec = lane & 15;

// ---- counted-vmcnt GEMM core, BM=128 x BN=256, BK=64, 8 waves, 3 LDS bufs ----
// r17 skeleton; ONE change: proper 3-bit bank swizzle. Source chunk
// (t&7)^((t>>3)&7) -> LDS(row,c) holds global chunk c^(row&7); fragment read
// XORs ((fr&7)<<3). Enumerated conflict-free (lanes 0-7 cover all 32 banks,
// lanes 8-15 repeat = 2-way = free).
__device__ __forceinline__ void gemm8c_core(const u16* __restrict__ A, const u16* __restrict__ B,
                                            int by, int bx, f32x4 (&acc)[4][4],
                                            u16 (*lds_a)[8192], u16 (*lds_b)[16384]) {
  const int t = threadIdx.x;
  const int w = t >> 6, lane = t & 63;
  const int wm = w >> 2, wn = w & 3;
  const int fr = lane & 15, lh = lane >> 4;
  const int xr = (fr & 7) << 3;                       // 3-bit fragment-read XOR
  const int kch = ((t & 7) ^ ((t >> 3) & 7)) * 8;     // 3-bit source pre-swizzle

  const u16* ga = A + (size_t)(by * 128 + (t >> 3)) * 1024 + kch;
  const u16* gb = B + (size_t)(bx * 256 + (t >> 3)) * 1024 + kch;

#pragma unroll
  for (int m = 0; m < 4; ++m)
#pragma unroll
    for (int n = 0; n < 4; ++n) acc[m][n] = {0.f, 0.f, 0.f, 0.f};

#define STAGE6(tile, buf)                                                      \
  do {                                                                         \
    gload16(ga + (size_t)0 * 65536 + (tile) * 64, &lds_a[buf][0 * 4096 + w * 512]); \
    gload16(ga + (size_t)1 * 65536 + (tile) * 64, &lds_a[buf][1 * 4096 + w * 512]); \
    gload16(gb + (size_t)0 * 65536 + (tile) * 64, &lds_b[buf][0 * 4096 + w * 512]); \
    gload16(gb + (size_t)1 * 65536 + (tile) * 64, &lds_b[buf][1 * 4096 + w * 512]); \
    gload16(gb + (size_t)2 * 65536 + (tile) * 64, &lds_b[buf][2 * 4096 + w * 512]); \
    gload16(gb + (size_t)3 * 65536 + (tile) * 64, &lds_b[buf][3 * 4096 + w * 512]); \
  } while (0)

  // prologue: tiles 0,1 in flight
  STAGE6(0, 0);
  STAGE6(1, 1);

  int buf = 0;       // consume buffer for tile kt
  int sbuf = 2;      // stage buffer for tile kt+2
  for (int kt = 0; kt < 16; ++kt) {
    if (kt < 15) { asm volatile("s_waitcnt vmcnt(6)" ::: "memory"); }
    else         { asm volatile("s_waitcnt vmcnt(0)" ::: "memory"); }
    __builtin_amdgcn_s_barrier();
    SCHED_FENCE();
    if (kt < 14) STAGE6(kt + 2, sbuf);
    SCHED_FENCE();

    bf16x8 bfr[4][2];
#pragma unroll
    for (int nn = 0; nn < 4; ++nn)
#pragma unroll
      for (int ks = 0; ks < 2; ++ks)
        bfr[nn][ks] = ld8(&lds_b[buf][(wn * 64 + nn * 16 + fr) * 64 + ((ks * 32 + lh * 8) ^ xr)]);
#pragma unroll
    for (int q = 0; q < 4; ++q) {
      if (q) __builtin_amdgcn_s_barrier();   // keep waves phase-interleaved
      bf16x8 af[2];
#pragma unroll
      for (int ks = 0; ks < 2; ++ks)
        af[ks] = ld8(&lds_a[buf][(wm * 64 + q * 16 + fr) * 64 + ((ks * 32 + lh * 8) ^ xr)]);
      __builtin_amdgcn_s_setprio(1);
#pragma unroll
      for (int nn = 0; nn < 4; ++nn)
#pragma unroll
        for (int ks = 0; ks < 2; ++ks)
          acc[q][nn] = __builtin_amdgcn_mfma_f32_16x16x32_bf16(af[ks], bfr[nn][ks], acc[q][nn], 0, 0, 0);
      __builtin_amdgcn_s_setprio(0);
    }
    buf = (buf == 2) ? 0 : buf + 1;
    sbuf = (sbuf == 2) ? 0 : sbuf + 1;
  }
#undef STAGE6
}

// Q/K/V projections, counted-vmcnt core. Grid 768 = 8 XCD x 96 = 3.0/CU.
// z=0: Q * QSCALE. z=1: K per-row chunk XOR. z=2: V^T + PV key perm + XOR.
__global__ __launch_bounds__(512)
void gemm8_qkv(const u16* __restrict__ Aall, const u16* __restrict__ Ball,
               u16* __restrict__ Call) {
  __shared__ alignas(16) u16 lds_a[3][8192];
  __shared__ alignas(16) u16 lds_b[3][16384];
  const int g = (blockIdx.x & 7) * 96 + (blockIdx.x >> 3);
  const int z = g >> 8, r8 = g & 255;
  const int by = r8 >> 2, bx = r8 & 3;
  const u16* A = Aall + (size_t)z * 8192 * 1024;
  const u16* B = Ball + (size_t)z * 1024 * 1024;
  u16* C = Call + (size_t)z * 8192 * 1024;

  f32x4 acc[4][4];
  gemm8c_core(A, B, by, bx, acc, lds_a, lds_b);

  const int t = threadIdx.x;
  const int w = t >> 6, lane = t & 63;
  const int wm = w >> 2, wn = w & 3;
  const int er = (lane >> 4) * 4, ec = lane & 15;
#pragma unroll
  for (int m = 0; m < 4; ++m)
#pragma unroll
    for (int nn = 0; nn < 4; ++nn) {
      const size_t row = (size_t)by * 128 + wm * 64 + m * 16 + er;
      const size_t col = (size_t)bx * 256 + wn * 64 + nn * 16 + ec;
      if (z == 0) {
#pragma unroll
        for (int rr = 0; rr < 4; ++rr)
          C[(row + rr) * 1024 + col] = f2bf(acc[m][nn][rr] * QSCALE);
      } else if (z == 1) {
        // K: swizzle dim chunk (8 dims = 16B) within head by key&7
#pragma unroll
        for (int rr = 0; rr < 4; ++rr) {
          const size_t n = row + rr;
          const size_t colswz = (col & ~(size_t)63) | ((col & 63) ^ ((n & 7) << 3));
          C[n * 1024 + colswz] = f2bf(acc[m][nn][rr]);
        }
      } else {
        // V^T per head: PV key permutation + key-chunk XOR by dim&7.
        ushort4 o4;
        o4.x = f2bf(acc[m][nn][0]); o4.y = f2bf(acc[m][nn][1]);
        o4.z = f2bf(acc[m][nn][2]); o4.w = f2bf(acc[m][nn][3]);
        const size_t nloc = row & 2047;
        const size_t d = col & 63;
        size_t pos = (nloc & ~(size_t)31) | (((nloc >> 2) & 3) << 3) |
                     (((nloc >> 4) & 1) << 2) | (nloc & 3);
        pos ^= (d & 7) << 3;
        const size_t idx = (((row >> 11) * 16 + (col >> 6)) * 64 + d) * 2048 + pos;
        *reinterpret_cast<ushort4*>(&C[idx]) = o4;
      }
    }
}

// Out-projection: m97 core (proven), f32 out + bias; grid 512 = 2.0/CU, XCD swizzle.
__global__ __launch_bounds__(256)
void gemm_out(const u16* __restrict__ A, const u16* __restrict__ B,
              float* __restrict__ Cf, const float* __restrict__ bias) {
  const int g = (blockIdx.x & 7) * 64 + (blockIdx.x >> 3);
  const int bx = g & 7, by = g >> 3;
  GEMM_CORE(A, B, 1024, bx, by)
#pragma unroll
  for (int i = 0; i < 4; ++i)
#pragma unroll
    for (int j = 0; j < 4; ++j) {
      const size_t row = row0 + wr * 64 + i * 16 + er;
      const size_t col = col0 + wc * 64 + j * 16 + ec;
#pragma unroll
      for (int r = 0; r < 4; ++r)
        Cf[(row + r) * 1024 + col] = acc[i][j][r] + bias[col];
    }
}

// Flash attention v9 (race-hardened, proven r13-r17 — unchanged).
__global__ __launch_bounds__(512)
void flash_attn(const u16* __restrict__ Q, const u16* __restrict__ Km,
                const u16* __restrict__ Vt, u16* __restrict__ O) {
  const int o_blk = (blockIdx.x & 7) * 64 + (blockIdx.x >> 3);
  const int qt = o_blk & 7, h = (o_blk >> 3) & 15, b = o_blk >> 7;
  const int t = threadIdx.x;
  const int w = t >> 6, lane = t & 63;
  const int l16 = lane & 15, lh = lane >> 4;

  __shared__ alignas(16) u16 kt_lds[2][64][64];
  __shared__ alignas(16) u16 vt_lds[2][64][64];

  const size_t base_qk = ((size_t)b * 2048) * 1024 + (size_t)h * 64;
  const size_t base_vt = ((size_t)(b * 16 + h)) * 64 * 2048;

  bf16x8 qf[2][2];
#pragma unroll
  for (int g = 0; g < 2; ++g) {
    const size_t qrow = (size_t)qt * 256 + (w * 2 + g) * 16 + l16;
    const u16* qp = Q + base_qk + qrow * 1024 + lh * 8;
    qf[g][0] = ld8(qp);
    qf[g][1] = ld8(qp + 32);
  }

  bf16x8 vones;
#pragma unroll
  for (int i = 0; i < 8; ++i) vones[i] = (__bf16)1.0f;

  f32x4 o_acc[2][4];
  f32x4 o_sum[2];
#pragma unroll
  for (int g = 0; g < 2; ++g) {
#pragma unroll
    for (int j = 0; j < 4; ++j) o_acc[g][j] = {0.f, 0.f, 0.f, 0.f};
    o_sum[g] = {0.f, 0.f, 0.f, 0.f};
  }

  const int srow = t >> 3;
  const int schk = (t & 7) * 8;
  const u16* kg = Km + base_qk + (size_t)srow * 1024 + schk;
  const u16* vg = Vt + base_vt + (size_t)srow * 2048 + schk;
  u16* kl0 = &kt_lds[0][0][0] + w * 512;
  u16* kl1 = &kt_lds[1][0][0] + w * 512;
  u16* vl0 = &vt_lds[0][0][0] + w * 512;
  u16* vl1 = &vt_lds[1][0][0] + w * 512;

  gload16(kg, kl0);
  gload16(vg, vl0);

  const int xo = (l16 & 7) << 3;

  for (int it = 0; it < 32; ++it) {
    const int cur = it & 1;
    asm volatile("s_waitcnt vmcnt(0)" ::: "memory");
    SCHED_FENCE();
    __syncthreads();
    SCHED_FENCE();

    if (it != 31) {
      const int nkv = (it + 1) * 64;
      gload16(kg + (size_t)nkv * 1024, cur ? kl0 : kl1);
      gload16(vg + nkv, cur ? vl0 : vl1);
    }
    SCHED_FENCE();

    f32x4 s[2][4];
#pragma unroll
    for (int g = 0; g < 2; ++g)
#pragma unroll
      for (int j = 0; j < 4; ++j) s[g][j] = {0.f, 0.f, 0.f, 0.f};
    __builtin_amdgcn_s_setprio(1);
#pragma unroll
    for (int j = 0; j < 4; ++j)
#pragma unroll
      for (int ks = 0; ks < 2; ++ks) {
        bf16x8 kf = ld8(&kt_lds[cur][j * 16 + l16][(ks * 32 + lh * 8) ^ xo]);
        s[0][j] = __builtin_amdgcn_mfma_f32_16x16x32_bf16(kf, qf[0][ks], s[0][j], 0, 0, 0);
        s[1][j] = __builtin_amdgcn_mfma_f32_16x16x32_bf16(kf, qf[1][ks], s[1][j], 0, 0, 0);
      }
    __builtin_amdgcn_s_setprio(0);

    bf16x8 pa[2][2];
#pragma unroll
    for (int g = 0; g < 2; ++g)
#pragma unroll
      for (int j = 0; j < 4; ++j)
#pragma unroll
        for (int r = 0; r < 4; ++r)
          s[g][j][r] = EXP2F(s[g][j][r]);
#pragma unroll
    for (int g = 0; g < 2; ++g)
#pragma unroll
      for (int c = 0; c < 2; ++c)
#pragma unroll
        for (int i = 0; i < 8; ++i)
          pa[g][c][i] = (__bf16)s[g][2 * c + (i >> 2)][i & 3];

    __builtin_amdgcn_s_setprio(1);
#pragma unroll
    for (int c = 0; c < 2; ++c) {
      o_sum[0] = __builtin_amdgcn_mfma_f32_16x16x32_bf16(pa[0][c], vones, o_sum[0], 0, 0, 0);
      o_sum[1] = __builtin_amdgcn_mfma_f32_16x16x32_bf16(pa[1][c], vones, o_sum[1], 0, 0, 0);
#pragma unroll
      for (int jd = 0; jd < 4; ++jd) {
        bf16x8 vf = ld8(&vt_lds[cur][jd * 16 + l16][(c * 32 + lh * 8) ^ xo]);
        o_acc[0][jd] = __builtin_amdgcn_mfma_f32_16x16x32_bf16(pa[0][c], vf, o_acc[0][jd], 0, 0, 0);
        o_acc[1][jd] = __builtin_amdgcn_mfma_f32_16x16x32_bf16(pa[1][c], vf, o_acc[1][jd], 0, 0, 0);
      }
    }
    __builtin_amdgcn_s_setprio(0);
  }

#pragma unroll
  for (int g = 0; g < 2; ++g) {
    float linv[4];
#pragma unroll
    for (int r = 0; r < 4; ++r) linv[r] = 1.0f / o_sum[g][r];
    const size_t orow0 = (size_t)b * 2048 + (size_t)qt * 256 + (w * 2 + g) * 16;
#pragma unroll
    for (int jd = 0; jd < 4; ++jd) {
      const int col = h * 64 + jd * 16 + l16;
#pragma unroll
      for (int r = 0; r < 4; ++r)
        O[(orow0 + lh * 4 + r) * 1024 + col] = f2bf(o_acc[g][jd][r] * linv[r]);
    }
  }
}

extern "C" void kernel_launch(void* const* d_in, const int* in_sizes, int n_in,
                              void* d_out, int out_size, void* d_ws, size_t ws_size,
                              hipStream_t stream) {
  const float* xq = (const float*)d_in[0];
  const float* xk = (const float*)d_in[1];
  const float* xv = (const float*)d_in[2];
  const float* Wq = (const float*)d_in[3];
  const float* Wk = (const float*)d_in[4];
  const float* Wv = (const float*)d_in[5];
  const float* Wo = (const float*)d_in[6];
  const float* bo = (const float*)d_in[7];
  float* out = (float*)d_out;

  const size_t X = (size_t)8192 * 1024;
  const size_t W = (size_t)1024 * 1024;

  u16* p = (u16*)d_ws;
  u16* x_bf  = p; p += 3 * X;          // xq | xk | xv (contiguous)
  u16* w_bf  = p; p += 4 * W;          // Wq | Wk | Wv | Wo
  u16* qkv   = p; p += 3 * X;          // Q | K(swz) | V^T(swz)
  u16* attn_bf = x_bf;                  // x_bf dead after projections; reuse

  dim3 blk(256);
  cast3_f32_to_bf16<<<dim3(8192, 3), blk, 0, stream>>>(xq, xk, xv, x_bf, (int)(X / 4));
  cast4_f32_to_bf16<<<dim3(1024, 4), blk, 0, stream>>>(Wq, Wk, Wv, Wo, w_bf, (int)(W / 4));

  gemm8_qkv<<<dim3(768), dim3(512), 0, stream>>>(x_bf, w_bf, qkv);

  flash_attn<<<dim3(512), dim3(512), 0, stream>>>(qkv, qkv + X, qkv + 2 * X, attn_bf);

  gemm_out<<<dim3(512), blk, 0, stream>>>(attn_bf, w_bf + 3 * W, out, bo);
}

// Round 19
// 192.906 us; speedup vs baseline: 1.0312x; 1.0302x over previous
//
#include <hip/hip_runtime.h>

typedef unsigned short u16;
using bf16x8 = __attribute__((ext_vector_type(8))) __bf16;
using f32x4  = __attribute__((ext_vector_type(4))) float;

// SCALE * log2(e): softmax runs in exp2 domain
#define QSCALE 0.18033688011f

#define EXP2F(x) __builtin_amdgcn_exp2f(x)
#define SCHED_FENCE() __builtin_amdgcn_sched_barrier(0)

__device__ __forceinline__ u16 f2bf(float f) {
  union { float f; unsigned int u; } x; x.f = f;
  unsigned int r = x.u + 0x7FFFu + ((x.u >> 16) & 1u);
  return (u16)(r >> 16);
}

__device__ __forceinline__ bf16x8 ld8(const u16* p) {
  return *reinterpret_cast<const bf16x8*>(p);
}

__device__ __forceinline__ void gload16(const void* g, void* l) {
  __builtin_amdgcn_global_load_lds(
      (const __attribute__((address_space(1))) unsigned int*)g,
      (__attribute__((address_space(3))) unsigned int*)l, 16, 0, 0);
}

__global__ void cast4_f32_to_bf16(const float* __restrict__ a, const float* __restrict__ b,
                                  const float* __restrict__ c, const float* __restrict__ d,
                                  u16* __restrict__ out, int n4) {
  const int y = blockIdx.y;
  const int i = blockIdx.x * 256 + threadIdx.x;
  if (i >= n4) return;
  const float* src = (y == 0) ? a : (y == 1) ? b : (y == 2) ? c : d;
  const float4 v = reinterpret_cast<const float4*>(src)[i];
  ushort4 o;
  o.x = f2bf(v.x); o.y = f2bf(v.y); o.z = f2bf(v.z); o.w = f2bf(v.w);
  reinterpret_cast<ushort4*>(out + (size_t)y * n4 * 4)[i] = o;
}

// ---- m97 GEMM core (128x128 tile, BK=32, gload_lds w=16, 2-barrier) ----
// r14 shape + 2-bit chunk swizzle on BOTH operands: source chunk (t&3)^((t>>2)&3),
// fragment read chunk lh^(fr&3). LDS(r,p) = global chunk p^(r&3); read retrieves
// wanted chunk g=lh. 8-way bank conflict -> 4-way.
#define GEMM_CORE(A_, B_, K_, BX_, BY_)                                              \
  __shared__ alignas(16) u16 lds_a[128 * 32];                                        \
  __shared__ alignas(16) u16 lds_b[128 * 32];                                        \
  const int t = threadIdx.x;                                                         \
  const int w = t >> 6, lane = t & 63;                                               \
  const int wr = w >> 1, wc = w & 1;                                                 \
  const size_t row0 = (size_t)(BY_) * 128;                                           \
  const size_t col0 = (size_t)(BX_) * 128;                                           \
  f32x4 acc[4][4];                                                                   \
  _Pragma("unroll") for (int i = 0; i < 4; ++i)                                      \
    _Pragma("unroll") for (int j = 0; j < 4; ++j) acc[i][j] = {0.f, 0.f, 0.f, 0.f};  \
  const int schk = ((t & 3) ^ ((t >> 2) & 3)) * 8;                                   \
  const u16* ga = A_ + (row0 + (t >> 2)) * K_ + schk;                                \
  const u16* gb = B_ + (col0 + (t >> 2)) * K_ + schk;                                \
  u16* la = lds_a + w * 512;                                                         \
  u16* lb = lds_b + w * 512;                                                         \
  const int fr = lane & 15;                                                          \
  const int flh = lane >> 4;                                                         \
  const int fko = ((flh ^ (fr & 3)) * 8);                                            \
  for (int kt = 0; kt < K_; kt += 32) {                                              \
    __syncthreads();                                                                 \
    gload16(ga + kt, la);                                                            \
    gload16(ga + (size_t)64 * K_ + kt, la + 2048);                                   \
    gload16(gb + kt, lb);                                                            \
    gload16(gb + (size_t)64 * K_ + kt, lb + 2048);                                   \
    asm volatile("s_waitcnt vmcnt(0)" ::: "memory");                                 \
    __syncthreads();                                                                 \
    bf16x8 af[4], bfr[4];                                                            \
    _Pragma("unroll") for (int i = 0; i < 4; ++i)                                    \
      af[i] = ld8(&lds_a[(wr * 64 + i * 16 + fr) * 32 + fko]);                       \
    _Pragma("unroll") for (int j = 0; j < 4; ++j)                                    \
      bfr[j] = ld8(&lds_b[(wc * 64 + j * 16 + fr) * 32 + fko]);                      \
    _Pragma("unroll") for (int i = 0; i < 4; ++i)                                    \
      _Pragma("unroll") for (int j = 0; j < 4; ++j)                                  \
        acc[i][j] = __builtin_amdgcn_mfma_f32_16x16x32_bf16(af[i], bfr[j], acc[i][j], 0, 0, 0); \
  }                                                                                  \
  const int er = (lane >> 4) * 4, ec = lane & 15;

// Q/K/V projections with fused f32->bf16 input cast (r14 proven structure):
// A staged as raw f32 via pure gload_lds (pre-swizzled source chunk, linear LDS,
// XOR+convert on fragment read); B via gload_lds with the 2-bit chunk swizzle.
// z=0: Q * QSCALE. z=1: K with per-row chunk XOR. z=2: V^T + PV key perm + XOR.
__global__ __launch_bounds__(256)
void gemm_qkv(const float* __restrict__ xq, const float* __restrict__ xk,
              const float* __restrict__ xv, const u16* __restrict__ Ball,
              u16* __restrict__ Call) {
  const int g = (blockIdx.x & 7) * 192 + (blockIdx.x >> 3);
  const int bx = g & 7, by = (g >> 3) & 63, z = g >> 9;
  const float* A = (z == 0) ? xq : (z == 1) ? xk : xv;
  const u16* B = Ball + (size_t)z * 1024 * 1024;
  u16* C = Call + (size_t)z * 8192 * 1024;

  __shared__ alignas(16) float lds_af[128 * 32];  // f32 A tile, chunk-XOR image
  __shared__ alignas(16) u16 lds_b[128 * 32];
  const int t = threadIdx.x;
  const int w = t >> 6, lane = t & 63;
  const int wr = w >> 1, wc = w & 1;
  const size_t row0 = (size_t)by * 128;
  const size_t col0 = (size_t)bx * 128;

  f32x4 acc[4][4];
#pragma unroll
  for (int i = 0; i < 4; ++i)
#pragma unroll
    for (int j = 0; j < 4; ++j) acc[i][j] = {0.f, 0.f, 0.f, 0.f};

  // A staging: thread t -> tile row t>>3, source chunk (t&7)^(row&7) (4-f32 chunks).
  const int arow = t >> 3;
  const int achk = (t & 7) ^ (arow & 7);
  const float* gaf = A + (row0 + arow) * 1024 + achk * 4;
  // B staging: 2-bit chunk swizzle.
  const int bchk = ((t & 3) ^ ((t >> 2) & 3)) * 8;
  const u16* gb = B + (col0 + (t >> 2)) * 1024 + bchk;
  float* laf = lds_af + w * 256;
  u16* lb = lds_b + w * 512;

  const int fr = lane & 15;
  const int flh = lane >> 4;
  const int fk = flh * 8;
  const int fx = fr & 7;                      // A fragment chunk XOR (3-bit, f32)
  const int fko = ((flh ^ (fr & 3)) * 8);     // B fragment chunk XOR (2-bit)

  for (int kt = 0; kt < 1024; kt += 32) {
    __syncthreads();
    gload16(gaf + kt, laf);
    gload16(gaf + kt + 32 * 1024, laf + 1024);
    gload16(gaf + kt + 64 * 1024, laf + 2048);
    gload16(gaf + kt + 96 * 1024, laf + 3072);
    gload16(gb + kt, lb);
    gload16(gb + (size_t)64 * 1024 + kt, lb + 2048);
    asm volatile("s_waitcnt vmcnt(0)" ::: "memory");
    __syncthreads();

    bf16x8 af[4], bfr[4];
#pragma unroll
    for (int i = 0; i < 4; ++i) {
      const int row = wr * 64 + i * 16 + fr;
      const int c0 = fk >> 2;      // {0,2,4,6}
      f32x4 lo = *reinterpret_cast<const f32x4*>(&lds_af[row * 32 + ((c0 ^ fx) << 2)]);
      f32x4 hi = *reinterpret_cast<const f32x4*>(&lds_af[row * 32 + (((c0 + 1) ^ fx) << 2)]);
      af[i][0] = (__bf16)lo[0]; af[i][1] = (__bf16)lo[1];
      af[i][2] = (__bf16)lo[2]; af[i][3] = (__bf16)lo[3];
      af[i][4] = (__bf16)hi[0]; af[i][5] = (__bf16)hi[1];
      af[i][6] = (__bf16)hi[2]; af[i][7] = (__bf16)hi[3];
    }
#pragma unroll
    for (int j = 0; j < 4; ++j)
      bfr[j] = ld8(&lds_b[(wc * 64 + j * 16 + fr) * 32 + fko]);
#pragma unroll
    for (int i = 0; i < 4; ++i)
#pragma unroll
      for (int j = 0; j < 4; ++j)
        acc[i][j] = __builtin_amdgcn_mfma_f32_16x16x32_bf16(af[i], bfr[j], acc[i][j], 0, 0, 0);
  }

  const int er = (lane >> 4) * 4, ec = lane & 15;
#pragma unroll
  for (int i = 0; i < 4; ++i)
#pragma unroll
    for (int j = 0; j < 4; ++j) {
      const size_t row = row0 + wr * 64 + i * 16 + er;
      const size_t col = col0 + wc * 64 + j * 16 + ec;
      if (z == 0) {
#pragma unroll
        for (int r = 0; r < 4; ++r)
          C[(row + r) * 1024 + col] = f2bf(acc[i][j][r] * QSCALE);
      } else if (z == 1) {
        // K: swizzle dim chunk (8 dims = 16B) within head by key&7
#pragma unroll
        for (int r = 0; r < 4; ++r) {
          const size_t n = row + r;
          const size_t colswz = (col & ~(size_t)63) |
                                ((col & 63) ^ (((n & 7) << 3)));
          C[n * 1024 + colswz] = f2bf(acc[i][j][r]);
        }
      } else {
        // V^T per head: PV key permutation + key-chunk XOR by dim&7.
        ushort4 o4;
        o4.x = f2bf(acc[i][j][0]); o4.y = f2bf(acc[i][j][1]);
        o4.z = f2bf(acc[i][j][2]); o4.w = f2bf(acc[i][j][3]);
        const size_t nloc = row & 2047;
        const size_t d = col & 63;
        size_t pos = (nloc & ~(size_t)31) | (((nloc >> 2) & 3) << 3) |
                     (((nloc >> 4) & 1) << 2) | (nloc & 3);
        pos ^= (d & 7) << 3;
        const size_t idx = (((row >> 11) * 16 + (col >> 6)) * 64 + d) * 2048 + pos;
        *reinterpret_cast<ushort4*>(&C[idx]) = o4;
      }
    }
}

// Out-projection: m97 core + swizzle, f32 out + bias; grid 512 = 2.0/CU, XCD swizzle.
__global__ __launch_bounds__(256)
void gemm_out(const u16* __restrict__ A, const u16* __restrict__ B,
              float* __restrict__ Cf, const float* __restrict__ bias) {
  const int g = (blockIdx.x & 7) * 64 + (blockIdx.x >> 3);
  const int bx = g & 7, by = g >> 3;
  GEMM_CORE(A, B, 1024, bx, by)
#pragma unroll
  for (int i = 0; i < 4; ++i)
#pragma unroll
    for (int j = 0; j < 4; ++j) {
      const size_t row = row0 + wr * 64 + i * 16 + er;
      const size_t col = col0 + wc * 64 + j * 16 + ec;
#pragma unroll
      for (int r = 0; r < 4; ++r)
        Cf[(row + r) * 1024 + col] = acc[i][j][r] + bias[col];
    }
}

// Flash attention v9 (race-hardened, proven r13-r18 — unchanged).
__global__ __launch_bounds__(512)
void flash_attn(const u16* __restrict__ Q, const u16* __restrict__ Km,
                const u16* __restrict__ Vt, u16* __restrict__ O) {
  const int o_blk = (blockIdx.x & 7) * 64 + (blockIdx.x >> 3);
  const int qt = o_blk & 7, h = (o_blk >> 3) & 15, b = o_blk >> 7;
  const int t = threadIdx.x;
  const int w = t >> 6, lane = t & 63;
  const int l16 = lane & 15, lh = lane >> 4;

  __shared__ alignas(16) u16 kt_lds[2][64][64];
  __shared__ alignas(16) u16 vt_lds[2][64][64];

  const size_t base_qk = ((size_t)b * 2048) * 1024 + (size_t)h * 64;
  const size_t base_vt = ((size_t)(b * 16 + h)) * 64 * 2048;

  bf16x8 qf[2][2];
#pragma unroll
  for (int g = 0; g < 2; ++g) {
    const size_t qrow = (size_t)qt * 256 + (w * 2 + g) * 16 + l16;
    const u16* qp = Q + base_qk + qrow * 1024 + lh * 8;
    qf[g][0] = ld8(qp);
    qf[g][1] = ld8(qp + 32);
  }

  bf16x8 vones;
#pragma unroll
  for (int i = 0; i < 8; ++i) vones[i] = (__bf16)1.0f;

  f32x4 o_acc[2][4];
  f32x4 o_sum[2];
#pragma unroll
  for (int g = 0; g < 2; ++g) {
#pragma unroll
    for (int j = 0; j < 4; ++j) o_acc[g][j] = {0.f, 0.f, 0.f, 0.f};
    o_sum[g] = {0.f, 0.f, 0.f, 0.f};
  }

  const int srow = t >> 3;
  const int schk = (t & 7) * 8;
  const u16* kg = Km + base_qk + (size_t)srow * 1024 + schk;
  const u16* vg = Vt + base_vt + (size_t)srow * 2048 + schk;
  u16* kl0 = &kt_lds[0][0][0] + w * 512;
  u16* kl1 = &kt_lds[1][0][0] + w * 512;
  u16* vl0 = &vt_lds[0][0][0] + w * 512;
  u16* vl1 = &vt_lds[1][0][0] + w * 512;

  gload16(kg, kl0);
  gload16(vg, vl0);

  const int xo = (l16 & 7) << 3;

  for (int it = 0; it < 32; ++it) {
    const int cur = it & 1;
    asm volatile("s_waitcnt vmcnt(0)" ::: "memory");
    SCHED_FENCE();
    __syncthreads();
    SCHED_FENCE();

    if (it != 31) {
      const int nkv = (it + 1) * 64;
      gload16(kg + (size_t)nkv * 1024, cur ? kl0 : kl1);
      gload16(vg + nkv, cur ? vl0 : vl1);
    }
    SCHED_FENCE();

    f32x4 s[2][4];
#pragma unroll
    for (int g = 0; g < 2; ++g)
#pragma unroll
      for (int j = 0; j < 4; ++j) s[g][j] = {0.f, 0.f, 0.f, 0.f};
    __builtin_amdgcn_s_setprio(1);
#pragma unroll
    for (int j = 0; j < 4; ++j)
#pragma unroll
      for (int ks = 0; ks < 2; ++ks) {
        bf16x8 kf = ld8(&kt_lds[cur][j * 16 + l16][(ks * 32 + lh * 8) ^ xo]);
        s[0][j] = __builtin_amdgcn_mfma_f32_16x16x32_bf16(kf, qf[0][ks], s[0][j], 0, 0, 0);
        s[1][j] = __builtin_amdgcn_mfma_f32_16x16x32_bf16(kf, qf[1][ks], s[1][j], 0, 0, 0);
      }
    __builtin_amdgcn_s_setprio(0);

    bf16x8 pa[2][2];
#pragma unroll
    for (int g = 0; g < 2; ++g)
#pragma unroll
      for (int j = 0; j < 4; ++j)
#pragma unroll
        for (int r = 0; r < 4; ++r)
          s[g][j][r] = EXP2F(s[g][j][r]);
#pragma unroll
    for (int g = 0; g < 2; ++g)
#pragma unroll
      for (int c = 0; c < 2; ++c)
#pragma unroll
        for (int i = 0; i < 8; ++i)
          pa[g][c][i] = (__bf16)s[g][2 * c + (i >> 2)][i & 3];

    __builtin_amdgcn_s_setprio(1);
#pragma unroll
    for (int c = 0; c < 2; ++c) {
      o_sum[0] = __builtin_amdgcn_mfma_f32_16x16x32_bf16(pa[0][c], vones, o_sum[0], 0, 0, 0);
      o_sum[1] = __builtin_amdgcn_mfma_f32_16x16x32_bf16(pa[1][c], vones, o_sum[1], 0, 0, 0);
#pragma unroll
      for (int jd = 0; jd < 4; ++jd) {
        bf16x8 vf = ld8(&vt_lds[cur][jd * 16 + l16][(c * 32 + lh * 8) ^ xo]);
        o_acc[0][jd] = __builtin_amdgcn_mfma_f32_16x16x32_bf16(pa[0][c], vf, o_acc[0][jd], 0, 0, 0);
        o_acc[1][jd] = __builtin_amdgcn_mfma_f32_16x16x32_bf16(pa[1][c], vf, o_acc[1][jd], 0, 0, 0);
      }
    }
    __builtin_amdgcn_s_setprio(0);
  }

#pragma unroll
  for (int g = 0; g < 2; ++g) {
    float linv[4];
#pragma unroll
    for (int r = 0; r < 4; ++r) linv[r] = 1.0f / o_sum[g][r];
    const size_t orow0 = (size_t)b * 2048 + (size_t)qt * 256 + (w * 2 + g) * 16;
#pragma unroll
    for (int jd = 0; jd < 4; ++jd) {
      const int col = h * 64 + jd * 16 + l16;
#pragma unroll
      for (int r = 0; r < 4; ++r)
        O[(orow0 + lh * 4 + r) * 1024 + col] = f2bf(o_acc[g][jd][r] * linv[r]);
    }
  }
}

extern "C" void kernel_launch(void* const* d_in, const int* in_sizes, int n_in,
                              void* d_out, int out_size, void* d_ws, size_t ws_size,
                              hipStream_t stream) {
  const float* xq = (const float*)d_in[0];
  const float* xk = (const float*)d_in[1];
  const float* xv = (const float*)d_in[2];
  const float* Wq = (const float*)d_in[3];
  const float* Wk = (const float*)d_in[4];
  const float* Wv = (const float*)d_in[5];
  const float* Wo = (const float*)d_in[6];
  const float* bo = (const float*)d_in[7];
  float* out = (float*)d_out;

  const size_t X = (size_t)8192 * 1024;
  const size_t W = (size_t)1024 * 1024;

  u16* p = (u16*)d_ws;
  u16* attn_bf = p; p += X;            // attention output (bf16)
  u16* w_bf  = p; p += 4 * W;          // Wq | Wk | Wv | Wo
  u16* qkv   = p; p += 3 * X;          // Q | K(swz) | V^T(swz)

  dim3 blk(256);
  cast4_f32_to_bf16<<<dim3(1024, 4), blk, 0, stream>>>(Wq, Wk, Wv, Wo, w_bf, (int)(W / 4));

  gemm_qkv<<<dim3(1536), blk, 0, stream>>>(xq, xk, xv, w_bf, qkv);

  flash_attn<<<dim3(512), dim3(512), 0, stream>>>(qkv, qkv + X, qkv + 2 * X, attn_bf);

  gemm_out<<<dim3(512), blk, 0, stream>>>(attn_bf, w_bf + 3 * W, out, bo);
}

// Round 21
// 178.634 us; speedup vs baseline: 1.1136x; 1.0799x over previous
//
#include <hip/hip_runtime.h>

typedef unsigned short u16;
using bf16x8 = __attribute__((ext_vector_type(8))) __bf16;
using f32x4  = __attribute__((ext_vector_type(4))) float;

// SCALE * log2(e): softmax runs in exp2 domain
#define QSCALE 0.18033688011f

#define EXP2F(x) __builtin_amdgcn_exp2f(x)
#define SCHED_FENCE() __builtin_amdgcn_sched_barrier(0)

__device__ __forceinline__ u16 f2bf(float f) {
  union { float f; unsigned int u; } x; x.f = f;
  unsigned int r = x.u + 0x7FFFu + ((x.u >> 16) & 1u);
  return (u16)(r >> 16);
}

__device__ __forceinline__ bf16x8 ld8(const u16* p) {
  return *reinterpret_cast<const bf16x8*>(p);
}

__device__ __forceinline__ void gload16(const void* g, void* l) {
  __builtin_amdgcn_global_load_lds(
      (const __attribute__((address_space(1))) unsigned int*)g,
      (__attribute__((address_space(3))) unsigned int*)l, 16, 0, 0);
}

__global__ void cast4_f32_to_bf16(const float* __restrict__ a, const float* __restrict__ b,
                                  const float* __restrict__ c, const float* __restrict__ d,
                                  u16* __restrict__ out, int n4) {
  const int y = blockIdx.y;
  const int i = blockIdx.x * 256 + threadIdx.x;
  if (i >= n4) return;
  const float* src = (y == 0) ? a : (y == 1) ? b : (y == 2) ? c : d;
  const float4 v = reinterpret_cast<const float4*>(src)[i];
  ushort4 o;
  o.x = f2bf(v.x); o.y = f2bf(v.y); o.z = f2bf(v.z); o.w = f2bf(v.w);
  reinterpret_cast<ushort4*>(out + (size_t)y * n4 * 4)[i] = o;
}

// ---- m97 GEMM core (128x128 tile, BK=32, gload_lds w=16, 2-barrier) ----
// Proven race-safe shape (r19). bx/by supplied by caller (XCD-swizzled).
#define GEMM_CORE(A_, B_, K_, BX_, BY_)                                              \
  __shared__ alignas(16) u16 lds_a[128 * 32];                                        \
  __shared__ alignas(16) u16 lds_b[128 * 32];                                        \
  const int t = threadIdx.x;                                                         \
  const int w = t >> 6, lane = t & 63;                                               \
  const int wr = w >> 1, wc = w & 1;                                                 \
  const size_t row0 = (size_t)(BY_) * 128;                                           \
  const size_t col0 = (size_t)(BX_) * 128;                                           \
  f32x4 acc[4][4];                                                                   \
  _Pragma("unroll") for (int i = 0; i < 4; ++i)                                      \
    _Pragma("unroll") for (int j = 0; j < 4; ++j) acc[i][j] = {0.f, 0.f, 0.f, 0.f};  \
  const int schk = ((t & 3) ^ ((t >> 2) & 3)) * 8;                                   \
  const u16* ga = A_ + (row0 + (t >> 2)) * K_ + schk;                                \
  const u16* gb = B_ + (col0 + (t >> 2)) * K_ + schk;                                \
  u16* la = lds_a + w * 512;                                                         \
  u16* lb = lds_b + w * 512;                                                         \
  const int fr = lane & 15;                                                          \
  const int flh = lane >> 4;                                                         \
  const int fko = ((flh ^ (fr & 3)) * 8);                                            \
  for (int kt = 0; kt < K_; kt += 32) {                                              \
    __syncthreads();                                                                 \
    gload16(ga + kt, la);                                                            \
    gload16(ga + (size_t)64 * K_ + kt, la + 2048);                                   \
    gload16(gb + kt, lb);                                                            \
    gload16(gb + (size_t)64 * K_ + kt, lb + 2048);                                   \
    asm volatile("s_waitcnt vmcnt(0)" ::: "memory");                                 \
    __syncthreads();                                                                 \
    bf16x8 af[4], bfr[4];                                                            \
    _Pragma("unroll") for (int i = 0; i < 4; ++i)                                    \
      af[i] = ld8(&lds_a[(wr * 64 + i * 16 + fr) * 32 + fko]);                       \
    _Pragma("unroll") for (int j = 0; j < 4; ++j)                                    \
      bfr[j] = ld8(&lds_b[(wc * 64 + j * 16 + fr) * 32 + fko]);                      \
    _Pragma("unroll") for (int i = 0; i < 4; ++i)                                    \
      _Pragma("unroll") for (int j = 0; j < 4; ++j)                                  \
        acc[i][j] = __builtin_amdgcn_mfma_f32_16x16x32_bf16(af[i], bfr[j], acc[i][j], 0, 0, 0); \
  }                                                                                  \
  const int er = (lane >> 4) * 4, ec = lane & 15;

// Q/K/V projections, fused f32 cast, BK=64 — wave-uniform-dest slab staging
// (rule #21 compliant): each gload issue fills one contiguous 4KB slab at
// slab_base + w*1024B, lane's 16B lands at +lane*16B.
//   A [128][64] f32: slab s=0..7 -> rows 16s+(t>>4), f32-chunk t&15,
//     source chunk (t&15)^((t>>4)&7)  => LDS(r,c) = global chunk c^(r&7).
//   B [128][64] u16: slab s=0..3 -> rows 32s+(t>>3), u16-chunk t&7,
//     source chunk (t&7)^((t>>3)&7)  => LDS(r,c) = global chunk c^(r&7).
// Fragment reads fetch c = g^(fr&7); k ascending (bit-exact canary).
__global__ __launch_bounds__(256)
void gemm_qkv(const float* __restrict__ xq, const float* __restrict__ xk,
              const float* __restrict__ xv, const u16* __restrict__ Ball,
              u16* __restrict__ Call) {
  const int g = (blockIdx.x & 7) * 192 + (blockIdx.x >> 3);
  const int bx = g & 7, by = (g >> 3) & 63, z = g >> 9;
  const float* A = (z == 0) ? xq : (z == 1) ? xk : xv;
  const u16* B = Ball + (size_t)z * 1024 * 1024;
  u16* C = Call + (size_t)z * 8192 * 1024;

  __shared__ alignas(16) float lds_af[128 * 64];  // 32 KB
  __shared__ alignas(16) u16 lds_b[128 * 64];     // 16 KB
  const int t = threadIdx.x;
  const int w = t >> 6, lane = t & 63;
  const int wr = w >> 1, wc = w & 1;
  const size_t row0 = (size_t)by * 128;
  const size_t col0 = (size_t)bx * 128;

  f32x4 acc[4][4];
#pragma unroll
  for (int i = 0; i < 4; ++i)
#pragma unroll
    for (int j = 0; j < 4; ++j) acc[i][j] = {0.f, 0.f, 0.f, 0.f};

  // A staging source: row 16s + (t>>4), f32 col chunk (t&15)^((t>>4)&7)
  const int a_r = t >> 4;
  const int a_c = ((t & 15) ^ (a_r & 7)) * 4;
  const float* gaf = A + (row0 + a_r) * 1024 + a_c;
  // B staging source: row 32s + (t>>3), u16 col chunk (t&7)^((t>>3)&7)
  const int b_r = t >> 3;
  const int b_c = ((t & 7) ^ (b_r & 7)) * 8;
  const u16* gbb = B + (col0 + b_r) * 1024 + b_c;

  const int fr = lane & 15;
  const int flh = lane >> 4;
  const int fx7 = fr & 7;

  for (int kt = 0; kt < 1024; kt += 64) {
    __syncthreads();
#pragma unroll
    for (int s = 0; s < 8; ++s)
      gload16(gaf + (size_t)(16 * s) * 1024 + kt, lds_af + s * 1024 + w * 256);
#pragma unroll
    for (int s = 0; s < 4; ++s)
      gload16(gbb + (size_t)(32 * s) * 1024 + kt, lds_b + s * 2048 + w * 512);
    asm volatile("s_waitcnt vmcnt(0)" ::: "memory");
    __syncthreads();

#pragma unroll
    for (int ks2 = 0; ks2 < 2; ++ks2) {   // two K=32 sub-passes, k ascending
      bf16x8 af[4], bfr[4];
#pragma unroll
      for (int i = 0; i < 4; ++i) {
        const int row = wr * 64 + i * 16 + fr;
        const int g0 = ks2 * 8 + flh * 2;          // f32 chunk pair (16 chunks/row)
        f32x4 lo = *reinterpret_cast<const f32x4*>(&lds_af[row * 64 + ((g0 ^ fx7) << 2)]);
        f32x4 hi = *reinterpret_cast<const f32x4*>(&lds_af[row * 64 + (((g0 + 1) ^ fx7) << 2)]);
        af[i][0] = (__bf16)lo[0]; af[i][1] = (__bf16)lo[1];
        af[i][2] = (__bf16)lo[2]; af[i][3] = (__bf16)lo[3];
        af[i][4] = (__bf16)hi[0]; af[i][5] = (__bf16)hi[1];
        af[i][6] = (__bf16)hi[2]; af[i][7] = (__bf16)hi[3];
      }
#pragma unroll
      for (int j = 0; j < 4; ++j) {
        const int row = wc * 64 + j * 16 + fr;
        const int gch = ks2 * 4 + flh;             // u16 chunk (8 chunks/row)
        bfr[j] = ld8(&lds_b[row * 64 + ((gch ^ fx7) * 8)]);
      }
#pragma unroll
      for (int i = 0; i < 4; ++i)
#pragma unroll
        for (int j = 0; j < 4; ++j)
          acc[i][j] = __builtin_amdgcn_mfma_f32_16x16x32_bf16(af[i], bfr[j], acc[i][j], 0, 0, 0);
    }
  }

  const int er = (lane >> 4) * 4, ec = lane & 15;
#pragma unroll
  for (int i = 0; i < 4; ++i)
#pragma unroll
    for (int j = 0; j < 4; ++j) {
      const size_t row = row0 + wr * 64 + i * 16 + er;
      const size_t col = col0 + wc * 64 + j * 16 + ec;
      if (z == 0) {
#pragma unroll
        for (int r = 0; r < 4; ++r)
          C[(row + r) * 1024 + col] = f2bf(acc[i][j][r] * QSCALE);
      } else if (z == 1) {
        // K: swizzle dim chunk (8 dims = 16B) within head by key&7
#pragma unroll
        for (int r = 0; r < 4; ++r) {
          const size_t n = row + r;
          const size_t colswz = (col & ~(size_t)63) |
                                ((col & 63) ^ (((n & 7) << 3)));
          C[n * 1024 + colswz] = f2bf(acc[i][j][r]);
        }
      } else {
        // V^T per head: PV key permutation + key-chunk XOR by dim&7.
        ushort4 o4;
        o4.x = f2bf(acc[i][j][0]); o4.y = f2bf(acc[i][j][1]);
        o4.z = f2bf(acc[i][j][2]); o4.w = f2bf(acc[i][j][3]);
        const size_t nloc = row & 2047;
        const size_t d = col & 63;
        size_t pos = (nloc & ~(size_t)31) | (((nloc >> 2) & 3) << 3) |
                     (((nloc >> 4) & 1) << 2) | (nloc & 3);
        pos ^= (d & 7) << 3;
        const size_t idx = (((row >> 11) * 16 + (col >> 6)) * 64 + d) * 2048 + pos;
        *reinterpret_cast<ushort4*>(&C[idx]) = o4;
      }
    }
}

// Out-projection: m97 core + swizzle, f32 out + bias; grid 512 = 2.0/CU, XCD swizzle.
__global__ __launch_bounds__(256)
void gemm_out(const u16* __restrict__ A, const u16* __restrict__ B,
              float* __restrict__ Cf, const float* __restrict__ bias) {
  const int g = (blockIdx.x & 7) * 64 + (blockIdx.x >> 3);
  const int bx = g & 7, by = g >> 3;
  GEMM_CORE(A, B, 1024, bx, by)
#pragma unroll
  for (int i = 0; i < 4; ++i)
#pragma unroll
    for (int j = 0; j < 4; ++j) {
      const size_t row = row0 + wr * 64 + i * 16 + er;
      const size_t col = col0 + wc * 64 + j * 16 + ec;
#pragma unroll
      for (int r = 0; r < 4; ++r)
        Cf[(row + r) * 1024 + col] = acc[i][j][r] + bias[col];
    }
}

// Flash attention v9 (race-hardened, proven r13-r19 — unchanged).
__global__ __launch_bounds__(512)
void flash_attn(const u16* __restrict__ Q, const u16* __restrict__ Km,
                const u16* __restrict__ Vt, u16* __restrict__ O) {
  const int o_blk = (blockIdx.x & 7) * 64 + (blockIdx.x >> 3);
  const int qt = o_blk & 7, h = (o_blk >> 3) & 15, b = o_blk >> 7;
  const int t = threadIdx.x;
  const int w = t >> 6, lane = t & 63;
  const int l16 = lane & 15, lh = lane >> 4;

  __shared__ alignas(16) u16 kt_lds[2][64][64];
  __shared__ alignas(16) u16 vt_lds[2][64][64];

  const size_t base_qk = ((size_t)b * 2048) * 1024 + (size_t)h * 64;
  const size_t base_vt = ((size_t)(b * 16 + h)) * 64 * 2048;

  bf16x8 qf[2][2];
#pragma unroll
  for (int g = 0; g < 2; ++g) {
    const size_t qrow = (size_t)qt * 256 + (w * 2 + g) * 16 + l16;
    const u16* qp = Q + base_qk + qrow * 1024 + lh * 8;
    qf[g][0] = ld8(qp);
    qf[g][1] = ld8(qp + 32);
  }

  bf16x8 vones;
#pragma unroll
  for (int i = 0; i < 8; ++i) vones[i] = (__bf16)1.0f;

  f32x4 o_acc[2][4];
  f32x4 o_sum[2];
#pragma unroll
  for (int g = 0; g < 2; ++g) {
#pragma unroll
    for (int j = 0; j < 4; ++j) o_acc[g][j] = {0.f, 0.f, 0.f, 0.f};
    o_sum[g] = {0.f, 0.f, 0.f, 0.f};
  }

  const int srow = t >> 3;
  const int schk = (t & 7) * 8;
  const u16* kg = Km + base_qk + (size_t)srow * 1024 + schk;
  const u16* vg = Vt + base_vt + (size_t)srow * 2048 + schk;
  u16* kl0 = &kt_lds[0][0][0] + w * 512;
  u16* kl1 = &kt_lds[1][0][0] + w * 512;
  u16* vl0 = &vt_lds[0][0][0] + w * 512;
  u16* vl1 = &vt_lds[1][0][0] + w * 512;

  gload16(kg, kl0);
  gload16(vg, vl0);

  const int xo = (l16 & 7) << 3;

  for (int it = 0; it < 32; ++it) {
    const int cur = it & 1;
    asm volatile("s_waitcnt vmcnt(0)" ::: "memory");
    SCHED_FENCE();
    __syncthreads();
    SCHED_FENCE();

    if (it != 31) {
      const int nkv = (it + 1) * 64;
      gload16(kg + (size_t)nkv * 1024, cur ? kl0 : kl1);
      gload16(vg + nkv, cur ? vl0 : vl1);
    }
    SCHED_FENCE();

    f32x4 s[2][4];
#pragma unroll
    for (int g = 0; g < 2; ++g)
#pragma unroll
      for (int j = 0; j < 4; ++j) s[g][j] = {0.f, 0.f, 0.f, 0.f};
    __builtin_amdgcn_s_setprio(1);
#pragma unroll
    for (int j = 0; j < 4; ++j)
#pragma unroll
      for (int ks = 0; ks < 2; ++ks) {
        bf16x8 kf = ld8(&kt_lds[cur][j * 16 + l16][(ks * 32 + lh * 8) ^ xo]);
        s[0][j] = __builtin_amdgcn_mfma_f32_16x16x32_bf16(kf, qf[0][ks], s[0][j], 0, 0, 0);
        s[1][j] = __builtin_amdgcn_mfma_f32_16x16x32_bf16(kf, qf[1][ks], s[1][j], 0, 0, 0);
      }
    __builtin_amdgcn_s_setprio(0);

    bf16x8 pa[2][2];
#pragma unroll
    for (int g = 0; g < 2; ++g)
#pragma unroll
      for (int j = 0; j < 4; ++j)
#pragma unroll
        for (int r = 0; r < 4; ++r)
          s[g][j][r] = EXP2F(s[g][j][r]);
#pragma unroll
    for (int g = 0; g < 2; ++g)
#pragma unroll
      for (int c = 0; c < 2; ++c)
#pragma unroll
        for (int i = 0; i < 8; ++i)
          pa[g][c][i] = (__bf16)s[g][2 * c + (i >> 2)][i & 3];

    __builtin_amdgcn_s_setprio(1);
#pragma unroll
    for (int c = 0; c < 2; ++c) {
      o_sum[0] = __builtin_amdgcn_mfma_f32_16x16x32_bf16(pa[0][c], vones, o_sum[0], 0, 0, 0);
      o_sum[1] = __builtin_amdgcn_mfma_f32_16x16x32_bf16(pa[1][c], vones, o_sum[1], 0, 0, 0);
#pragma unroll
      for (int jd = 0; jd < 4; ++jd) {
        bf16x8 vf = ld8(&vt_lds[cur][jd * 16 + l16][(c * 32 + lh * 8) ^ xo]);
        o_acc[0][jd] = __builtin_amdgcn_mfma_f32_16x16x32_bf16(pa[0][c], vf, o_acc[0][jd], 0, 0, 0);
        o_acc[1][jd] = __builtin_amdgcn_mfma_f32_16x16x32_bf16(pa[1][c], vf, o_acc[1][jd], 0, 0, 0);
      }
    }
    __builtin_amdgcn_s_setprio(0);
  }

#pragma unroll
  for (int g = 0; g < 2; ++g) {
    float linv[4];
#pragma unroll
    for (int r = 0; r < 4; ++r) linv[r] = 1.0f / o_sum[g][r];
    const size_t orow0 = (size_t)b * 2048 + (size_t)qt * 256 + (w * 2 + g) * 16;
#pragma unroll
    for (int jd = 0; jd < 4; ++jd) {
      const int col = h * 64 + jd * 16 + l16;
#pragma unroll
      for (int r = 0; r < 4; ++r)
        O[(orow0 + lh * 4 + r) * 1024 + col] = f2bf(o_acc[g][jd][r] * linv[r]);
    }
  }
}

extern "C" void kernel_launch(void* const* d_in, const int* in_sizes, int n_in,
                              void* d_out, int out_size, void* d_ws, size_t ws_size,
                              hipStream_t stream) {
  const float* xq = (const float*)d_in[0];
  const float* xk = (const float*)d_in[1];
  const float* xv = (const float*)d_in[2];
  const float* Wq = (const float*)d_in[3];
  const float* Wk = (const float*)d_in[4];
  const float* Wv = (const float*)d_in[5];
  const float* Wo = (const float*)d_in[6];
  const float* bo = (const float*)d_in[7];
  float* out = (float*)d_out;

  const size_t X = (size_t)8192 * 1024;
  const size_t W = (size_t)1024 * 1024;

  u16* p = (u16*)d_ws;
  u16* attn_bf = p; p += X;            // attention output (bf16)
  u16* w_bf  = p; p += 4 * W;          // Wq | Wk | Wv | Wo
  u16* qkv   = p; p += 3 * X;          // Q | K(swz) | V^T(swz)

  dim3 blk(256);
  cast4_f32_to_bf16<<<dim3(1024, 4), blk, 0, stream>>>(Wq, Wk, Wv, Wo, w_bf, (int)(W / 4));

  gemm_qkv<<<dim3(1536), blk, 0, stream>>>(xq, xk, xv, w_bf, qkv);

  flash_attn<<<dim3(512), dim3(512), 0, stream>>>(qkv, qkv + X, qkv + 2 * X, attn_bf);

  gemm_out<<<dim3(512), blk, 0, stream>>>(attn_bf, w_bf + 3 * W, out, bo);
}

// Round 22
// 176.620 us; speedup vs baseline: 1.1263x; 1.0114x over previous
//
#include <hip/hip_runtime.h>

typedef unsigned short u16;
using bf16x8 = __attribute__((ext_vector_type(8))) __bf16;
using f32x4  = __attribute__((ext_vector_type(4))) float;

// SCALE * log2(e): softmax runs in exp2 domain
#define QSCALE 0.18033688011f

#define EXP2F(x) __builtin_amdgcn_exp2f(x)
#define SCHED_FENCE() __builtin_amdgcn_sched_barrier(0)

__device__ __forceinline__ u16 f2bf(float f) {
  union { float f; unsigned int u; } x; x.f = f;
  unsigned int r = x.u + 0x7FFFu + ((x.u >> 16) & 1u);
  return (u16)(r >> 16);
}

__device__ __forceinline__ bf16x8 ld8(const u16* p) {
  return *reinterpret_cast<const bf16x8*>(p);
}

__device__ __forceinline__ void gload16(const void* g, void* l) {
  __builtin_amdgcn_global_load_lds(
      (const __attribute__((address_space(1))) unsigned int*)g,
      (__attribute__((address_space(3))) unsigned int*)l, 16, 0, 0);
}

__global__ void cast4_f32_to_bf16(const float* __restrict__ a, const float* __restrict__ b,
                                  const float* __restrict__ c, const float* __restrict__ d,
                                  u16* __restrict__ out, int n4) {
  const int y = blockIdx.y;
  const int i = blockIdx.x * 256 + threadIdx.x;
  if (i >= n4) return;
  const float* src = (y == 0) ? a : (y == 1) ? b : (y == 2) ? c : d;
  const float4 v = reinterpret_cast<const float4*>(src)[i];
  ushort4 o;
  o.x = f2bf(v.x); o.y = f2bf(v.y); o.z = f2bf(v.z); o.w = f2bf(v.w);
  reinterpret_cast<ushort4*>(out + (size_t)y * n4 * 4)[i] = o;
}

// Q/K/V projections, fused f32 cast, BK=64, wave-uniform-dest slab staging
// (r21 proven: barrier-halving = -14 us).
//   A [128][64] f32: slab s=0..7 -> rows 16s+(t>>4), f32-chunk t&15,
//     source chunk (t&15)^((t>>4)&7)  => LDS(r,c) = global chunk c^(r&7).
//   B [128][64] u16: slab s=0..3 -> rows 32s+(t>>3), u16-chunk t&7,
//     source chunk (t&7)^((t>>3)&7)  => LDS(r,c) = global chunk c^(r&7).
// Fragment reads fetch c = g^(fr&7); k ascending (bit-exact canary).
__global__ __launch_bounds__(256)
void gemm_qkv(const float* __restrict__ xq, const float* __restrict__ xk,
              const float* __restrict__ xv, const u16* __restrict__ Ball,
              u16* __restrict__ Call) {
  const int g = (blockIdx.x & 7) * 192 + (blockIdx.x >> 3);
  const int bx = g & 7, by = (g >> 3) & 63, z = g >> 9;
  const float* A = (z == 0) ? xq : (z == 1) ? xk : xv;
  const u16* B = Ball + (size_t)z * 1024 * 1024;
  u16* C = Call + (size_t)z * 8192 * 1024;

  __shared__ alignas(16) float lds_af[128 * 64];  // 32 KB
  __shared__ alignas(16) u16 lds_b[128 * 64];     // 16 KB
  const int t = threadIdx.x;
  const int w = t >> 6, lane = t & 63;
  const int wr = w >> 1, wc = w & 1;
  const size_t row0 = (size_t)by * 128;
  const size_t col0 = (size_t)bx * 128;

  f32x4 acc[4][4];
#pragma unroll
  for (int i = 0; i < 4; ++i)
#pragma unroll
    for (int j = 0; j < 4; ++j) acc[i][j] = {0.f, 0.f, 0.f, 0.f};

  const int a_r = t >> 4;
  const int a_c = ((t & 15) ^ (a_r & 7)) * 4;
  const float* gaf = A + (row0 + a_r) * 1024 + a_c;
  const int b_r = t >> 3;
  const int b_c = ((t & 7) ^ (b_r & 7)) * 8;
  const u16* gbb = B + (col0 + b_r) * 1024 + b_c;

  const int fr = lane & 15;
  const int flh = lane >> 4;
  const int fx7 = fr & 7;

  for (int kt = 0; kt < 1024; kt += 64) {
    __syncthreads();
#pragma unroll
    for (int s = 0; s < 8; ++s)
      gload16(gaf + (size_t)(16 * s) * 1024 + kt, lds_af + s * 1024 + w * 256);
#pragma unroll
    for (int s = 0; s < 4; ++s)
      gload16(gbb + (size_t)(32 * s) * 1024 + kt, lds_b + s * 2048 + w * 512);
    asm volatile("s_waitcnt vmcnt(0)" ::: "memory");
    __syncthreads();

#pragma unroll
    for (int ks2 = 0; ks2 < 2; ++ks2) {   // two K=32 sub-passes, k ascending
      bf16x8 af[4], bfr[4];
#pragma unroll
      for (int i = 0; i < 4; ++i) {
        const int row = wr * 64 + i * 16 + fr;
        const int g0 = ks2 * 8 + flh * 2;          // f32 chunk pair (16 chunks/row)
        f32x4 lo = *reinterpret_cast<const f32x4*>(&lds_af[row * 64 + ((g0 ^ fx7) << 2)]);
        f32x4 hi = *reinterpret_cast<const f32x4*>(&lds_af[row * 64 + (((g0 + 1) ^ fx7) << 2)]);
        af[i][0] = (__bf16)lo[0]; af[i][1] = (__bf16)lo[1];
        af[i][2] = (__bf16)lo[2]; af[i][3] = (__bf16)lo[3];
        af[i][4] = (__bf16)hi[0]; af[i][5] = (__bf16)hi[1];
        af[i][6] = (__bf16)hi[2]; af[i][7] = (__bf16)hi[3];
      }
#pragma unroll
      for (int j = 0; j < 4; ++j) {
        const int row = wc * 64 + j * 16 + fr;
        const int gch = ks2 * 4 + flh;             // u16 chunk (8 chunks/row)
        bfr[j] = ld8(&lds_b[row * 64 + ((gch ^ fx7) * 8)]);
      }
#pragma unroll
      for (int i = 0; i < 4; ++i)
#pragma unroll
        for (int j = 0; j < 4; ++j)
          acc[i][j] = __builtin_amdgcn_mfma_f32_16x16x32_bf16(af[i], bfr[j], acc[i][j], 0, 0, 0);
    }
  }

  const int er = (lane >> 4) * 4, ec = lane & 15;
#pragma unroll
  for (int i = 0; i < 4; ++i)
#pragma unroll
    for (int j = 0; j < 4; ++j) {
      const size_t row = row0 + wr * 64 + i * 16 + er;
      const size_t col = col0 + wc * 64 + j * 16 + ec;
      if (z == 0) {
#pragma unroll
        for (int r = 0; r < 4; ++r)
          C[(row + r) * 1024 + col] = f2bf(acc[i][j][r] * QSCALE);
      } else if (z == 1) {
        // K: swizzle dim chunk (8 dims = 16B) within head by key&7
#pragma unroll
        for (int r = 0; r < 4; ++r) {
          const size_t n = row + r;
          const size_t colswz = (col & ~(size_t)63) |
                                ((col & 63) ^ (((n & 7) << 3)));
          C[n * 1024 + colswz] = f2bf(acc[i][j][r]);
        }
      } else {
        // V^T per head: PV key permutation + key-chunk XOR by dim&7.
        ushort4 o4;
        o4.x = f2bf(acc[i][j][0]); o4.y = f2bf(acc[i][j][1]);
        o4.z = f2bf(acc[i][j][2]); o4.w = f2bf(acc[i][j][3]);
        const size_t nloc = row & 2047;
        const size_t d = col & 63;
        size_t pos = (nloc & ~(size_t)31) | (((nloc >> 2) & 3) << 3) |
                     (((nloc >> 4) & 1) << 2) | (nloc & 3);
        pos ^= (d & 7) << 3;
        const size_t idx = (((row >> 11) * 16 + (col >> 6)) * 64 + d) * 2048 + pos;
        *reinterpret_cast<ushort4*>(&C[idx]) = o4;
      }
    }
}

// Out-projection, BK=64 slab-staged (r21 lever applied; both operands bf16,
// LDS 32 KB): slab s=0..3 rows 32s+(t>>3), source chunk (t&7)^((t>>3)&7);
// fragment reads c=g^(fr&7); two K=32 sub-passes k-ascending. f32 out + bias.
// Grid 512 = 2.0/CU, XCD swizzle.
__global__ __launch_bounds__(256)
void gemm_out(const u16* __restrict__ A, const u16* __restrict__ B,
              float* __restrict__ Cf, const float* __restrict__ bias) {
  const int g = (blockIdx.x & 7) * 64 + (blockIdx.x >> 3);
  const int bx = g & 7, by = g >> 3;

  __shared__ alignas(16) u16 lds_a[128 * 64];   // 16 KB
  __shared__ alignas(16) u16 lds_b[128 * 64];   // 16 KB
  const int t = threadIdx.x;
  const int w = t >> 6, lane = t & 63;
  const int wr = w >> 1, wc = w & 1;
  const size_t row0 = (size_t)by * 128;
  const size_t col0 = (size_t)bx * 128;

  f32x4 acc[4][4];
#pragma unroll
  for (int i = 0; i < 4; ++i)
#pragma unroll
    for (int j = 0; j < 4; ++j) acc[i][j] = {0.f, 0.f, 0.f, 0.f};

  const int b_r = t >> 3;
  const int b_c = ((t & 7) ^ (b_r & 7)) * 8;
  const u16* gaa = A + (row0 + b_r) * 1024 + b_c;
  const u16* gbb = B + (col0 + b_r) * 1024 + b_c;

  const int fr = lane & 15;
  const int flh = lane >> 4;
  const int fx7 = fr & 7;

  for (int kt = 0; kt < 1024; kt += 64) {
    __syncthreads();
#pragma unroll
    for (int s = 0; s < 4; ++s) {
      gload16(gaa + (size_t)(32 * s) * 1024 + kt, lds_a + s * 2048 + w * 512);
      gload16(gbb + (size_t)(32 * s) * 1024 + kt, lds_b + s * 2048 + w * 512);
    }
    asm volatile("s_waitcnt vmcnt(0)" ::: "memory");
    __syncthreads();

#pragma unroll
    for (int ks2 = 0; ks2 < 2; ++ks2) {
      bf16x8 af[4], bfr[4];
      const int gch = ks2 * 4 + flh;
#pragma unroll
      for (int i = 0; i < 4; ++i)
        af[i] = ld8(&lds_a[(wr * 64 + i * 16 + fr) * 64 + ((gch ^ fx7) * 8)]);
#pragma unroll
      for (int j = 0; j < 4; ++j)
        bfr[j] = ld8(&lds_b[(wc * 64 + j * 16 + fr) * 64 + ((gch ^ fx7) * 8)]);
#pragma unroll
      for (int i = 0; i < 4; ++i)
#pragma unroll
        for (int j = 0; j < 4; ++j)
          acc[i][j] = __builtin_amdgcn_mfma_f32_16x16x32_bf16(af[i], bfr[j], acc[i][j], 0, 0, 0);
    }
  }

  const int er = (lane >> 4) * 4, ec = lane & 15;
#pragma unroll
  for (int i = 0; i < 4; ++i)
#pragma unroll
    for (int j = 0; j < 4; ++j) {
      const size_t row = row0 + wr * 64 + i * 16 + er;
      const size_t col = col0 + wc * 64 + j * 16 + ec;
#pragma unroll
      for (int r = 0; r < 4; ++r)
        Cf[(row + r) * 1024 + col] = acc[i][j][r] + bias[col];
    }
}

// Flash attention v9 (race-hardened, proven r13-r21 — unchanged).
__global__ __launch_bounds__(512)
void flash_attn(const u16* __restrict__ Q, const u16* __restrict__ Km,
                const u16* __restrict__ Vt, u16* __restrict__ O) {
  const int o_blk = (blockIdx.x & 7) * 64 + (blockIdx.x >> 3);
  const int qt = o_blk & 7, h = (o_blk >> 3) & 15, b = o_blk >> 7;
  const int t = threadIdx.x;
  const int w = t >> 6, lane = t & 63;
  const int l16 = lane & 15, lh = lane >> 4;

  __shared__ alignas(16) u16 kt_lds[2][64][64];
  __shared__ alignas(16) u16 vt_lds[2][64][64];

  const size_t base_qk = ((size_t)b * 2048) * 1024 + (size_t)h * 64;
  const size_t base_vt = ((size_t)(b * 16 + h)) * 64 * 2048;

  bf16x8 qf[2][2];
#pragma unroll
  for (int g = 0; g < 2; ++g) {
    const size_t qrow = (size_t)qt * 256 + (w * 2 + g) * 16 + l16;
    const u16* qp = Q + base_qk + qrow * 1024 + lh * 8;
    qf[g][0] = ld8(qp);
    qf[g][1] = ld8(qp + 32);
  }

  bf16x8 vones;
#pragma unroll
  for (int i = 0; i < 8; ++i) vones[i] = (__bf16)1.0f;

  f32x4 o_acc[2][4];
  f32x4 o_sum[2];
#pragma unroll
  for (int g = 0; g < 2; ++g) {
#pragma unroll
    for (int j = 0; j < 4; ++j) o_acc[g][j] = {0.f, 0.f, 0.f, 0.f};
    o_sum[g] = {0.f, 0.f, 0.f, 0.f};
  }

  const int srow = t >> 3;
  const int schk = (t & 7) * 8;
  const u16* kg = Km + base_qk + (size_t)srow * 1024 + schk;
  const u16* vg = Vt + base_vt + (size_t)srow * 2048 + schk;
  u16* kl0 = &kt_lds[0][0][0] + w * 512;
  u16* kl1 = &kt_lds[1][0][0] + w * 512;
  u16* vl0 = &vt_lds[0][0][0] + w * 512;
  u16* vl1 = &vt_lds[1][0][0] + w * 512;

  gload16(kg, kl0);
  gload16(vg, vl0);

  const int xo = (l16 & 7) << 3;

  for (int it = 0; it < 32; ++it) {
    const int cur = it & 1;
    asm volatile("s_waitcnt vmcnt(0)" ::: "memory");
    SCHED_FENCE();
    __syncthreads();
    SCHED_FENCE();

    if (it != 31) {
      const int nkv = (it + 1) * 64;
      gload16(kg + (size_t)nkv * 1024, cur ? kl0 : kl1);
      gload16(vg + nkv, cur ? vl0 : vl1);
    }
    SCHED_FENCE();

    f32x4 s[2][4];
#pragma unroll
    for (int g = 0; g < 2; ++g)
#pragma unroll
      for (int j = 0; j < 4; ++j) s[g][j] = {0.f, 0.f, 0.f, 0.f};
    __builtin_amdgcn_s_setprio(1);
#pragma unroll
    for (int j = 0; j < 4; ++j)
#pragma unroll
      for (int ks = 0; ks < 2; ++ks) {
        bf16x8 kf = ld8(&kt_lds[cur][j * 16 + l16][(ks * 32 + lh * 8) ^ xo]);
        s[0][j] = __builtin_amdgcn_mfma_f32_16x16x32_bf16(kf, qf[0][ks], s[0][j], 0, 0, 0);
        s[1][j] = __builtin_amdgcn_mfma_f32_16x16x32_bf16(kf, qf[1][ks], s[1][j], 0, 0, 0);
      }
    __builtin_amdgcn_s_setprio(0);

    bf16x8 pa[2][2];
#pragma unroll
    for (int g = 0; g < 2; ++g)
#pragma unroll
      for (int j = 0; j < 4; ++j)
#pragma unroll
        for (int r = 0; r < 4; ++r)
          s[g][j][r] = EXP2F(s[g][j][r]);
#pragma unroll
    for (int g = 0; g < 2; ++g)
#pragma unroll
      for (int c = 0; c < 2; ++c)
#pragma unroll
        for (int i = 0; i < 8; ++i)
          pa[g][c][i] = (__bf16)s[g][2 * c + (i >> 2)][i & 3];

    __builtin_amdgcn_s_setprio(1);
#pragma unroll
    for (int c = 0; c < 2; ++c) {
      o_sum[0] = __builtin_amdgcn_mfma_f32_16x16x32_bf16(pa[0][c], vones, o_sum[0], 0, 0, 0);
      o_sum[1] = __builtin_amdgcn_mfma_f32_16x16x32_bf16(pa[1][c], vones, o_sum[1], 0, 0, 0);
#pragma unroll
      for (int jd = 0; jd < 4; ++jd) {
        bf16x8 vf = ld8(&vt_lds[cur][jd * 16 + l16][(c * 32 + lh * 8) ^ xo]);
        o_acc[0][jd] = __builtin_amdgcn_mfma_f32_16x16x32_bf16(pa[0][c], vf, o_acc[0][jd], 0, 0, 0);
        o_acc[1][jd] = __builtin_amdgcn_mfma_f32_16x16x32_bf16(pa[1][c], vf, o_acc[1][jd], 0, 0, 0);
      }
    }
    __builtin_amdgcn_s_setprio(0);
  }

#pragma unroll
  for (int g = 0; g < 2; ++g) {
    float linv[4];
#pragma unroll
    for (int r = 0; r < 4; ++r) linv[r] = 1.0f / o_sum[g][r];
    const size_t orow0 = (size_t)b * 2048 + (size_t)qt * 256 + (w * 2 + g) * 16;
#pragma unroll
    for (int jd = 0; jd < 4; ++jd) {
      const int col = h * 64 + jd * 16 + l16;
#pragma unroll
      for (int r = 0; r < 4; ++r)
        O[(orow0 + lh * 4 + r) * 1024 + col] = f2bf(o_acc[g][jd][r] * linv[r]);
    }
  }
}

extern "C" void kernel_launch(void* const* d_in, const int* in_sizes, int n_in,
                              void* d_out, int out_size, void* d_ws, size_t ws_size,
                              hipStream_t stream) {
  const float* xq = (const float*)d_in[0];
  const float* xk = (const float*)d_in[1];
  const float* xv = (const float*)d_in[2];
  const float* Wq = (const float*)d_in[3];
  const float* Wk = (const float*)d_in[4];
  const float* Wv = (const float*)d_in[5];
  const float* Wo = (const float*)d_in[6];
  const float* bo = (const float*)d_in[7];
  float* out = (float*)d_out;

  const size_t X = (size_t)8192 * 1024;
  const size_t W = (size_t)1024 * 1024;

  u16* p = (u16*)d_ws;
  u16* attn_bf = p; p += X;            // attention output (bf16)
  u16* w_bf  = p; p += 4 * W;          // Wq | Wk | Wv | Wo
  u16* qkv   = p; p += 3 * X;          // Q | K(swz) | V^T(swz)

  dim3 blk(256);
  cast4_f32_to_bf16<<<dim3(1024, 4), blk, 0, stream>>>(Wq, Wk, Wv, Wo, w_bf, (int)(W / 4));

  gemm_qkv<<<dim3(1536), blk, 0, stream>>>(xq, xk, xv, w_bf, qkv);

  flash_attn<<<dim3(512), dim3(512), 0, stream>>>(qkv, qkv + X, qkv + 2 * X, attn_bf);

  gemm_out<<<dim3(512), blk, 0, stream>>>(attn_bf, w_bf + 3 * W, out, bo);
}

// Round 23
// 175.159 us; speedup vs baseline: 1.1357x; 1.0083x over previous
//
#include <hip/hip_runtime.h>

typedef unsigned short u16;
using bf16x8 = __attribute__((ext_vector_type(8))) __bf16;
using f32x4  = __attribute__((ext_vector_type(4))) float;

// SCALE * log2(e): softmax runs in exp2 domain
#define QSCALE 0.18033688011f

#define EXP2F(x) __builtin_amdgcn_exp2f(x)
#define SCHED_FENCE() __builtin_amdgcn_sched_barrier(0)

__device__ __forceinline__ u16 f2bf(float f) {
  union { float f; unsigned int u; } x; x.f = f;
  unsigned int r = x.u + 0x7FFFu + ((x.u >> 16) & 1u);
  return (u16)(r >> 16);
}

__device__ __forceinline__ bf16x8 ld8(const u16* p) {
  return *reinterpret_cast<const bf16x8*>(p);
}

__device__ __forceinline__ void gload16(const void* g, void* l) {
  __builtin_amdgcn_global_load_lds(
      (const __attribute__((address_space(1))) unsigned int*)g,
      (__attribute__((address_space(3))) unsigned int*)l, 16, 0, 0);
}

__global__ void cast4_f32_to_bf16(const float* __restrict__ a, const float* __restrict__ b,
                                  const float* __restrict__ c, const float* __restrict__ d,
                                  u16* __restrict__ out, int n4) {
  const int y = blockIdx.y;
  const int i = blockIdx.x * 256 + threadIdx.x;
  if (i >= n4) return;
  const float* src = (y == 0) ? a : (y == 1) ? b : (y == 2) ? c : d;
  const float4 v = reinterpret_cast<const float4*>(src)[i];
  ushort4 o;
  o.x = f2bf(v.x); o.y = f2bf(v.y); o.z = f2bf(v.z); o.w = f2bf(v.w);
  reinterpret_cast<ushort4*>(out + (size_t)y * n4 * 4)[i] = o;
}

// Q/K/V projections, fused f32 cast, BK=32 DOUBLE-BUFFERED (flash-style loop:
// drain -> barrier -> stage next tile into other buf -> compute; load latency
// hidden under the compute phase). LDS 48 KB (A f32 2x16KB, B 2x8KB), 3 blk/CU.
//   A [128][32] f32: slab s=0..3 rows 32s+(t>>3), src chunk (t&7)^((t>>3)&7)
//     => LDS(r,c) = global chunk c^(r&7); read c = g^(fr&7).
//   B [128][32] u16: slab s=0..1 rows 64s+(t>>2), src chunk (t&3)^((t>>2)&3)
//     => LDS(r,c) = global chunk c^(r&3); read c = flh^(fr&3) (r19-proven).
// k ascending (bit-exact canary).
__global__ __launch_bounds__(256)
void gemm_qkv(const float* __restrict__ xq, const float* __restrict__ xk,
              const float* __restrict__ xv, const u16* __restrict__ Ball,
              u16* __restrict__ Call) {
  const int g = (blockIdx.x & 7) * 192 + (blockIdx.x >> 3);
  const int bx = g & 7, by = (g >> 3) & 63, z = g >> 9;
  const float* A = (z == 0) ? xq : (z == 1) ? xk : xv;
  const u16* B = Ball + (size_t)z * 1024 * 1024;
  u16* C = Call + (size_t)z * 8192 * 1024;

  __shared__ alignas(16) float lds_af[2][128 * 32];  // 2 x 16 KB
  __shared__ alignas(16) u16 lds_b[2][128 * 32];     // 2 x 8 KB
  const int t = threadIdx.x;
  const int w = t >> 6, lane = t & 63;
  const int wr = w >> 1, wc = w & 1;
  const size_t row0 = (size_t)by * 128;
  const size_t col0 = (size_t)bx * 128;

  f32x4 acc[4][4];
#pragma unroll
  for (int i = 0; i < 4; ++i)
#pragma unroll
    for (int j = 0; j < 4; ++j) acc[i][j] = {0.f, 0.f, 0.f, 0.f};

  // A staging source: row t>>3 (+32s), f32 chunk (t&7)^((t>>3)&7)
  const int a_r = t >> 3;
  const int a_c = ((t & 7) ^ (a_r & 7)) * 4;
  const float* gaf = A + (row0 + a_r) * 1024 + a_c;
  // B staging source: row t>>2 (+64s), u16 chunk (t&3)^((t>>2)&3)
  const int b_r = t >> 2;
  const int b_c = ((t & 3) ^ (b_r & 3)) * 8;
  const u16* gbb = B + (col0 + b_r) * 1024 + b_c;

  const int fr = lane & 15;
  const int flh = lane >> 4;
  const int fx7 = fr & 7;
  const int fko = ((flh ^ (fr & 3)) * 8);

#define STAGEQ(tile, buf)                                                          \
  do {                                                                             \
    _Pragma("unroll") for (int s = 0; s < 4; ++s)                                  \
      gload16(gaf + (size_t)(32 * s) * 1024 + (tile) * 32,                         \
              &lds_af[buf][s * 1024 + w * 256]);                                   \
    _Pragma("unroll") for (int s = 0; s < 2; ++s)                                  \
      gload16(gbb + (size_t)(64 * s) * 1024 + (tile) * 32,                         \
              &lds_b[buf][s * 2048 + w * 512]);                                    \
  } while (0)

  STAGEQ(0, 0);

  for (int it = 0; it < 32; ++it) {
    const int cur = it & 1;
    asm volatile("s_waitcnt vmcnt(0)" ::: "memory");
    SCHED_FENCE();
    __syncthreads();
    SCHED_FENCE();

    if (it != 31) STAGEQ(it + 1, cur ^ 1);
    SCHED_FENCE();

    bf16x8 af[4], bfr[4];
#pragma unroll
    for (int i = 0; i < 4; ++i) {
      const int row = wr * 64 + i * 16 + fr;
      const int g0 = flh * 2;            // f32 chunk pair (8 chunks/row)
      f32x4 lo = *reinterpret_cast<const f32x4*>(&lds_af[cur][row * 32 + ((g0 ^ fx7) << 2)]);
      f32x4 hi = *reinterpret_cast<const f32x4*>(&lds_af[cur][row * 32 + (((g0 + 1) ^ fx7) << 2)]);
      af[i][0] = (__bf16)lo[0]; af[i][1] = (__bf16)lo[1];
      af[i][2] = (__bf16)lo[2]; af[i][3] = (__bf16)lo[3];
      af[i][4] = (__bf16)hi[0]; af[i][5] = (__bf16)hi[1];
      af[i][6] = (__bf16)hi[2]; af[i][7] = (__bf16)hi[3];
    }
#pragma unroll
    for (int j = 0; j < 4; ++j)
      bfr[j] = ld8(&lds_b[cur][(wc * 64 + j * 16 + fr) * 32 + fko]);
#pragma unroll
    for (int i = 0; i < 4; ++i)
#pragma unroll
      for (int j = 0; j < 4; ++j)
        acc[i][j] = __builtin_amdgcn_mfma_f32_16x16x32_bf16(af[i], bfr[j], acc[i][j], 0, 0, 0);
  }
#undef STAGEQ

  const int er = (lane >> 4) * 4, ec = lane & 15;
#pragma unroll
  for (int i = 0; i < 4; ++i)
#pragma unroll
    for (int j = 0; j < 4; ++j) {
      const size_t row = row0 + wr * 64 + i * 16 + er;
      const size_t col = col0 + wc * 64 + j * 16 + ec;
      if (z == 0) {
#pragma unroll
        for (int r = 0; r < 4; ++r)
          C[(row + r) * 1024 + col] = f2bf(acc[i][j][r] * QSCALE);
      } else if (z == 1) {
        // K: swizzle dim chunk (8 dims = 16B) within head by key&7
#pragma unroll
        for (int r = 0; r < 4; ++r) {
          const size_t n = row + r;
          const size_t colswz = (col & ~(size_t)63) |
                                ((col & 63) ^ (((n & 7) << 3)));
          C[n * 1024 + colswz] = f2bf(acc[i][j][r]);
        }
      } else {
        // V^T per head: PV key permutation + key-chunk XOR by dim&7.
        ushort4 o4;
        o4.x = f2bf(acc[i][j][0]); o4.y = f2bf(acc[i][j][1]);
        o4.z = f2bf(acc[i][j][2]); o4.w = f2bf(acc[i][j][3]);
        const size_t nloc = row & 2047;
        const size_t d = col & 63;
        size_t pos = (nloc & ~(size_t)31) | (((nloc >> 2) & 3) << 3) |
                     (((nloc >> 4) & 1) << 2) | (nloc & 3);
        pos ^= (d & 7) << 3;
        const size_t idx = (((row >> 11) * 16 + (col >> 6)) * 64 + d) * 2048 + pos;
        *reinterpret_cast<ushort4*>(&C[idx]) = o4;
      }
    }
}

// Out-projection, BK=64 slab-staged (r22 proven): both operands bf16, LDS 32 KB;
// slab s=0..3 rows 32s+(t>>3), source chunk (t&7)^((t>>3)&7); fragment reads
// c=g^(fr&7); two K=32 sub-passes k-ascending. f32 out + bias. Grid 512, XCD swz.
__global__ __launch_bounds__(256)
void gemm_out(const u16* __restrict__ A, const u16* __restrict__ B,
              float* __restrict__ Cf, const float* __restrict__ bias) {
  const int g = (blockIdx.x & 7) * 64 + (blockIdx.x >> 3);
  const int bx = g & 7, by = g >> 3;

  __shared__ alignas(16) u16 lds_a[128 * 64];   // 16 KB
  __shared__ alignas(16) u16 lds_b[128 * 64];   // 16 KB
  const int t = threadIdx.x;
  const int w = t >> 6, lane = t & 63;
  const int wr = w >> 1, wc = w & 1;
  const size_t row0 = (size_t)by * 128;
  const size_t col0 = (size_t)bx * 128;

  f32x4 acc[4][4];
#pragma unroll
  for (int i = 0; i < 4; ++i)
#pragma unroll
    for (int j = 0; j < 4; ++j) acc[i][j] = {0.f, 0.f, 0.f, 0.f};

  const int b_r = t >> 3;
  const int b_c = ((t & 7) ^ (b_r & 7)) * 8;
  const u16* gaa = A + (row0 + b_r) * 1024 + b_c;
  const u16* gbb = B + (col0 + b_r) * 1024 + b_c;

  const int fr = lane & 15;
  const int flh = lane >> 4;
  const int fx7 = fr & 7;

  for (int kt = 0; kt < 1024; kt += 64) {
    __syncthreads();
#pragma unroll
    for (int s = 0; s < 4; ++s) {
      gload16(gaa + (size_t)(32 * s) * 1024 + kt, lds_a + s * 2048 + w * 512);
      gload16(gbb + (size_t)(32 * s) * 1024 + kt, lds_b + s * 2048 + w * 512);
    }
    asm volatile("s_waitcnt vmcnt(0)" ::: "memory");
    __syncthreads();

#pragma unroll
    for (int ks2 = 0; ks2 < 2; ++ks2) {
      bf16x8 af[4], bfr[4];
      const int gch = ks2 * 4 + flh;
#pragma unroll
      for (int i = 0; i < 4; ++i)
        af[i] = ld8(&lds_a[(wr * 64 + i * 16 + fr) * 64 + ((gch ^ fx7) * 8)]);
#pragma unroll
      for (int j = 0; j < 4; ++j)
        bfr[j] = ld8(&lds_b[(wc * 64 + j * 16 + fr) * 64 + ((gch ^ fx7) * 8)]);
#pragma unroll
      for (int i = 0; i < 4; ++i)
#pragma unroll
        for (int j = 0; j < 4; ++j)
          acc[i][j] = __builtin_amdgcn_mfma_f32_16x16x32_bf16(af[i], bfr[j], acc[i][j], 0, 0, 0);
    }
  }

  const int er = (lane >> 4) * 4, ec = lane & 15;
#pragma unroll
  for (int i = 0; i < 4; ++i)
#pragma unroll
    for (int j = 0; j < 4; ++j) {
      const size_t row = row0 + wr * 64 + i * 16 + er;
      const size_t col = col0 + wc * 64 + j * 16 + ec;
#pragma unroll
      for (int r = 0; r < 4; ++r)
        Cf[(row + r) * 1024 + col] = acc[i][j][r] + bias[col];
    }
}

// Flash attention v9 (race-hardened, proven r13-r22 — unchanged).
__global__ __launch_bounds__(512)
void flash_attn(const u16* __restrict__ Q, const u16* __restrict__ Km,
                const u16* __restrict__ Vt, u16* __restrict__ O) {
  const int o_blk = (blockIdx.x & 7) * 64 + (blockIdx.x >> 3);
  const int qt = o_blk & 7, h = (o_blk >> 3) & 15, b = o_blk >> 7;
  const int t = threadIdx.x;
  const int w = t >> 6, lane = t & 63;
  const int l16 = lane & 15, lh = lane >> 4;

  __shared__ alignas(16) u16 kt_lds[2][64][64];
  __shared__ alignas(16) u16 vt_lds[2][64][64];

  const size_t base_qk = ((size_t)b * 2048) * 1024 + (size_t)h * 64;
  const size_t base_vt = ((size_t)(b * 16 + h)) * 64 * 2048;

  bf16x8 qf[2][2];
#pragma unroll
  for (int g = 0; g < 2; ++g) {
    const size_t qrow = (size_t)qt * 256 + (w * 2 + g) * 16 + l16;
    const u16* qp = Q + base_qk + qrow * 1024 + lh * 8;
    qf[g][0] = ld8(qp);
    qf[g][1] = ld8(qp + 32);
  }

  bf16x8 vones;
#pragma unroll
  for (int i = 0; i < 8; ++i) vones[i] = (__bf16)1.0f;

  f32x4 o_acc[2][4];
  f32x4 o_sum[2];
#pragma unroll
  for (int g = 0; g < 2; ++g) {
#pragma unroll
    for (int j = 0; j < 4; ++j) o_acc[g][j] = {0.f, 0.f, 0.f, 0.f};
    o_sum[g] = {0.f, 0.f, 0.f, 0.f};
  }

  const int srow = t >> 3;
  const int schk = (t & 7) * 8;
  const u16* kg = Km + base_qk + (size_t)srow * 1024 + schk;
  const u16* vg = Vt + base_vt + (size_t)srow * 2048 + schk;
  u16* kl0 = &kt_lds[0][0][0] + w * 512;
  u16* kl1 = &kt_lds[1][0][0] + w * 512;
  u16* vl0 = &vt_lds[0][0][0] + w * 512;
  u16* vl1 = &vt_lds[1][0][0] + w * 512;

  gload16(kg, kl0);
  gload16(vg, vl0);

  const int xo = (l16 & 7) << 3;

  for (int it = 0; it < 32; ++it) {
    const int cur = it & 1;
    asm volatile("s_waitcnt vmcnt(0)" ::: "memory");
    SCHED_FENCE();
    __syncthreads();
    SCHED_FENCE();

    if (it != 31) {
      const int nkv = (it + 1) * 64;
      gload16(kg + (size_t)nkv * 1024, cur ? kl0 : kl1);
      gload16(vg + nkv, cur ? vl0 : vl1);
    }
    SCHED_FENCE();

    f32x4 s[2][4];
#pragma unroll
    for (int g = 0; g < 2; ++g)
#pragma unroll
      for (int j = 0; j < 4; ++j) s[g][j] = {0.f, 0.f, 0.f, 0.f};
    __builtin_amdgcn_s_setprio(1);
#pragma unroll
    for (int j = 0; j < 4; ++j)
#pragma unroll
      for (int ks = 0; ks < 2; ++ks) {
        bf16x8 kf = ld8(&kt_lds[cur][j * 16 + l16][(ks * 32 + lh * 8) ^ xo]);
        s[0][j] = __builtin_amdgcn_mfma_f32_16x16x32_bf16(kf, qf[0][ks], s[0][j], 0, 0, 0);
        s[1][j] = __builtin_amdgcn_mfma_f32_16x16x32_bf16(kf, qf[1][ks], s[1][j], 0, 0, 0);
      }
    __builtin_amdgcn_s_setprio(0);

    bf16x8 pa[2][2];
#pragma unroll
    for (int g = 0; g < 2; ++g)
#pragma unroll
      for (int j = 0; j < 4; ++j)
#pragma unroll
        for (int r = 0; r < 4; ++r)
          s[g][j][r] = EXP2F(s[g][j][r]);
#pragma unroll
    for (int g = 0; g < 2; ++g)
#pragma unroll
      for (int c = 0; c < 2; ++c)
#pragma unroll
        for (int i = 0; i < 8; ++i)
          pa[g][c][i] = (__bf16)s[g][2 * c + (i >> 2)][i & 3];

    __builtin_amdgcn_s_setprio(1);
#pragma unroll
    for (int c = 0; c < 2; ++c) {
      o_sum[0] = __builtin_amdgcn_mfma_f32_16x16x32_bf16(pa[0][c], vones, o_sum[0], 0, 0, 0);
      o_sum[1] = __builtin_amdgcn_mfma_f32_16x16x32_bf16(pa[1][c], vones, o_sum[1], 0, 0, 0);
#pragma unroll
      for (int jd = 0; jd < 4; ++jd) {
        bf16x8 vf = ld8(&vt_lds[cur][jd * 16 + l16][(c * 32 + lh * 8) ^ xo]);
        o_acc[0][jd] = __builtin_amdgcn_mfma_f32_16x16x32_bf16(pa[0][c], vf, o_acc[0][jd], 0, 0, 0);
        o_acc[1][jd] = __builtin_amdgcn_mfma_f32_16x16x32_bf16(pa[1][c], vf, o_acc[1][jd], 0, 0, 0);
      }
    }
    __builtin_amdgcn_s_setprio(0);
  }

#pragma unroll
  for (int g = 0; g < 2; ++g) {
    float linv[4];
#pragma unroll
    for (int r = 0; r < 4; ++r) linv[r] = 1.0f / o_sum[g][r];
    const size_t orow0 = (size_t)b * 2048 + (size_t)qt * 256 + (w * 2 + g) * 16;
#pragma unroll
    for (int jd = 0; jd < 4; ++jd) {
      const int col = h * 64 + jd * 16 + l16;
#pragma unroll
      for (int r = 0; r < 4; ++r)
        O[(orow0 + lh * 4 + r) * 1024 + col] = f2bf(o_acc[g][jd][r] * linv[r]);
    }
  }
}

extern "C" void kernel_launch(void* const* d_in, const int* in_sizes, int n_in,
                              void* d_out, int out_size, void* d_ws, size_t ws_size,
                              hipStream_t stream) {
  const float* xq = (const float*)d_in[0];
  const float* xk = (const float*)d_in[1];
  const float* xv = (const float*)d_in[2];
  const float* Wq = (const float*)d_in[3];
  const float* Wk = (const float*)d_in[4];
  const float* Wv = (const float*)d_in[5];
  const float* Wo = (const float*)d_in[6];
  const float* bo = (const float*)d_in[7];
  float* out = (float*)d_out;

  const size_t X = (size_t)8192 * 1024;
  const size_t W = (size_t)1024 * 1024;

  u16* p = (u16*)d_ws;
  u16* attn_bf = p; p += X;            // attention output (bf16)
  u16* w_bf  = p; p += 4 * W;          // Wq | Wk | Wv | Wo
  u16* qkv   = p; p += 3 * X;          // Q | K(swz) | V^T(swz)

  dim3 blk(256);
  cast4_f32_to_bf16<<<dim3(1024, 4), blk, 0, stream>>>(Wq, Wk, Wv, Wo, w_bf, (int)(W / 4));

  gemm_qkv<<<dim3(1536), blk, 0, stream>>>(xq, xk, xv, w_bf, qkv);

  flash_attn<<<dim3(512), dim3(512), 0, stream>>>(qkv, qkv + X, qkv + 2 * X, attn_bf);

  gemm_out<<<dim3(512), blk, 0, stream>>>(attn_bf, w_bf + 3 * W, out, bo);
}